// Round 7
// baseline (1086.561 us; speedup 1.0000x reference)
//
#include <hip/hip_runtime.h>

#define NN 10000
#define NE 100000
#define ND 128
#define NB 20
#define NIR 224
#define NH 352
#define SD 480
#define BS 512
#define NTILE (NE / 32)

// CG / normalization constants (verified in R1/R2)
#define CR   0.70710678118654752f
#define CA   0.40824829046386302f
#define HA   0.20412414523193151f
#define HR   0.35355339059327376f
#define C110 0.57735026918962576f
#define C220 0.44721359549995794f
#define C111 0.40824829046386302f
#define C11X 0.44721359549995794f
#define C221 0.36514837167011074f
#define C222 0.58554004376912270f
#define S32  0.86602540378443865f
#define PW0  0.066815310478106094f
#define PW1  0.088388347648318447f
#define PW2  0.11918321088232916f

typedef __bf16 v8bf __attribute__((ext_vector_type(8)));
typedef unsigned short us8v __attribute__((ext_vector_type(8)));
typedef float f32x4 __attribute__((ext_vector_type(4)));

__device__ __forceinline__ unsigned short f2bfc(float f) {
  __bf16 h = (__bf16)f;
  return __builtin_bit_cast(unsigned short, h);
}
__device__ __forceinline__ float bf2f(unsigned short h) {
  unsigned int u = ((unsigned int)h) << 16;
  return __builtin_bit_cast(float, u);
}

__device__ __forceinline__ float warpReduceSum(float v) {
  #pragma unroll
  for (int off = 32; off > 0; off >>= 1) v += __shfl_down(v, off, 64);
  return v;
}

// component-major index mapping for spherical rows
__device__ __forceinline__ int t2tT(int t) {
  if (t < 128) return t;
  if (t < 320) { int c = t - 128; return 128 + (c % 3) * 64 + c / 3; }
  int c = t - 320; return 320 + (c % 5) * 32 + c / 5;
}

// ---------------- Sort kernels: counting sort of edges by dst ----------------
__global__ __launch_bounds__(256) void sort_hist(const int* __restrict__ ei, int* __restrict__ cnt) {
  int e = blockIdx.x * 256 + threadIdx.x;
  if (e < NE) atomicAdd(&cnt[ei[e]], 1);
}

__global__ __launch_bounds__(1024) void sort_scan(const int* __restrict__ cnt, int* __restrict__ cursor) {
  __shared__ int part[1024];
  const int t = threadIdx.x;
  int loc[10]; int s = 0;
  #pragma unroll
  for (int j = 0; j < 10; ++j) { int idx = t * 10 + j; int v = (idx < NN) ? cnt[idx] : 0; loc[j] = s; s += v; }
  part[t] = s; __syncthreads();
  for (int d = 1; d < 1024; d <<= 1) {
    int v = (t >= d) ? part[t - d] : 0; __syncthreads();
    part[t] += v; __syncthreads();
  }
  int off = part[t] - s;
  #pragma unroll
  for (int j = 0; j < 10; ++j) { int idx = t * 10 + j; if (idx < NN) cursor[idx] = off + loc[j]; }
}

__global__ __launch_bounds__(256) void sort_scatter(
    const int* __restrict__ ei, int* __restrict__ cursor,
    int* __restrict__ es_dst, int* __restrict__ es_src, int* __restrict__ es_eid) {
  int e = blockIdx.x * 256 + threadIdx.x;
  if (e < NE) {
    int d = ei[e];
    int pos = atomicAdd(&cursor[d], 1);
    es_dst[pos] = d; es_src[pos] = ei[NE + e]; es_eid[pos] = e;
  }
}

// ---------------- Kernel 1: scalar LN + O3 LN (writes sphT component-major) --
__global__ __launch_bounds__(128) void node_ln_kernel(
    const float* __restrict__ xs, const float* __restrict__ xsph,
    const float* __restrict__ lnw, const float* __restrict__ lnb,
    const float* __restrict__ o3w, const float* __restrict__ o3b,
    float* __restrict__ s_in, float* __restrict__ sphT,
    float* __restrict__ out0)
{
  const int n = blockIdx.x, t = threadIdx.x;
  __shared__ float red[4];

  auto reduce2 = [&](float a, float b) {
    a = warpReduceSum(a); b = warpReduceSum(b);
    if ((t & 63) == 0) { red[(t >> 6) * 2] = a; red[(t >> 6) * 2 + 1] = b; }
    __syncthreads();
    float ra = red[0] + red[2], rb = red[1] + red[3];
    __syncthreads();
    return make_float2(ra, rb);
  };

  float x = xs[n * ND + t];
  float2 sr = reduce2(x, x * x);
  float mu = sr.x * (1.f / ND);
  float var = sr.y * (1.f / ND) - mu * mu;
  float y = (x - mu) * rsqrtf(var + 1e-5f) * lnw[t] + lnb[t];
  s_in[n * ND + t] = y; out0[n * ND + t] = y;

  float f = xsph[n * SD + t];
  float2 r0 = reduce2(f, f * f);
  float m0 = r0.x * (1.f / 128.f);
  float nrm0 = r0.y * (1.f / 128.f) - m0 * m0;
  float y0 = (f - m0) * rsqrtf(nrm0 + 1e-5f) * o3w[t] + o3b[t];
  sphT[n * SD + t] = y0;

  float f1a = xsph[n * SD + 128 + t];
  float f1b = (t < 64) ? xsph[n * SD + 256 + t] : 0.f;
  float2 r1 = reduce2(f1a * f1a + f1b * f1b, 0.f);
  float rs1 = rsqrtf(r1.x * (1.f / 192.f) + 1e-5f);
  sphT[n * SD + t2tT(128 + t)] = f1a * rs1 * o3w[128 + t / 3];
  if (t < 64)
    sphT[n * SD + t2tT(256 + t)] = f1b * rs1 * o3w[128 + (128 + t) / 3];

  float f2a = xsph[n * SD + 320 + t];
  float f2b = (t < 32) ? xsph[n * SD + 448 + t] : 0.f;
  float2 r2 = reduce2(f2a * f2a + f2b * f2b, 0.f);
  float rs2 = rsqrtf(r2.x * (1.f / 160.f) + 1e-5f);
  sphT[n * SD + t2tT(320 + t)] = f2a * rs2 * o3w[192 + t / 5];
  if (t < 32)
    sphT[n * SD + t2tT(448 + t)] = f2b * rs2 * o3w[192 + (128 + t) / 5];
}

// ---------------- Kernel 2: node MLP (unchanged, verified) ------------------
#define NPB 8
__global__ __launch_bounds__(256) void mlp_kernel(
    const float* __restrict__ s_in, const float* __restrict__ w1,
    const float* __restrict__ b1, const float* __restrict__ w2,
    const float* __restrict__ b2, float* __restrict__ s_out)
{
  __shared__ float sIn[NPB][ND];
  __shared__ float sH[NPB][ND];
  const int t = threadIdx.x;
  const int n0 = blockIdx.x * NPB;
  for (int i = t; i < NPB * ND; i += 256) sIn[i >> 7][i & 127] = s_in[n0 * ND + i];
  __syncthreads();
  {
    const int j = t & 127, g = t >> 7;
    float acc[4] = {0.f, 0.f, 0.f, 0.f};
    for (int k = 0; k < ND; ++k) {
      float w = w1[k * ND + j];
      #pragma unroll
      for (int i = 0; i < 4; ++i) acc[i] = fmaf(sIn[g + 2 * i][k], w, acc[i]);
    }
    #pragma unroll
    for (int i = 0; i < 4; ++i) {
      float z = acc[i] + b1[j];
      sH[g + 2 * i][j] = z / (1.f + __expf(-z));
    }
  }
  __syncthreads();
  for (int jb = 0; jb < 2; ++jb) {
    int j = jb * 256 + t;
    if (j < NH) {
      float acc[NPB];
      #pragma unroll
      for (int i = 0; i < NPB; ++i) acc[i] = b2[j];
      for (int k = 0; k < ND; ++k) {
        float w = w2[k * NH + j];
        #pragma unroll
        for (int i = 0; i < NPB; ++i) acc[i] = fmaf(sH[i][k], w, acc[i]);
      }
      #pragma unroll
      for (int i = 0; i < NPB; ++i) s_out[(n0 + i) * NH + j] = acc[i];
    }
  }
}

// ---------------- W element fetchers (tpw fp32 layout, verified offsets) ----
__device__ __forceinline__ float wc0(const float* w, int u, int j) {
  int off = (u < 128) ? u * 128 : (u < 192) ? 16384 + (u - 128) * 128 : 24576 + (u - 192) * 128;
  return w[off + j];
}
__device__ __forceinline__ float wc1(const float* w, int u, int j) {
  int off = (u < 128) ? 28672 + u * 64 : (u < 192) ? 36864 + (u - 128) * 64
          : (u < 256) ? 40960 + (u - 192) * 64 : (u < 320) ? 45056 + (u - 256) * 64
          : (u < 352) ? 49152 + (u - 320) * 64 : 51200 + (u - 352) * 64;
  return w[off + j];
}
__device__ __forceinline__ float wc2(const float* w, int u, int j) {
  int off = (u < 128) ? 53248 + u * 32 : (u < 192) ? 57344 + (u - 128) * 32
          : (u < 256) ? 59392 + (u - 192) * 32 : (u < 288) ? 61440 + (u - 256) * 32
          : (u < 320) ? 62464 + (u - 288) * 32 : 63488 + (u - 320) * 32;
  return w[off + j];
}

// ---------------- Prep kernel: pre-swizzle W into bf16 fragment layout ------
__global__ __launch_bounds__(256) void prep_w_kernel(
    const float* __restrict__ tpw, const float* __restrict__ rbf_w,
    unsigned short* __restrict__ W0g, unsigned short* __restrict__ W1g,
    unsigned short* __restrict__ W2g, unsigned short* __restrict__ Wfq)
{
  int gid = blockIdx.x * 256 + threadIdx.x;
  int i = gid & 7, lane = (gid >> 3) & 63;
  int r = lane & 15, kl = lane >> 4;
  if (gid < 28672) {
    int fid = gid >> 9, kk = fid >> 3, wid = fid & 7;
    W0g[gid] = f2bfc(wc0(tpw, kk * 32 + kl * 8 + i, wid * 16 + r));
  } else if (gid < 53248) {
    int g = gid - 28672, fid = g >> 9, kk = fid >> 2, nt = fid & 3;
    W1g[g] = f2bfc(wc1(tpw, kk * 32 + kl * 8 + i, nt * 16 + r));
  } else if (gid < 65536) {
    int g = gid - 53248, fid = g >> 9, q = fid >> 2, kh = (fid >> 1) & 1, ntc = fid & 1;
    int kk = kh * 6 + q;
    W2g[g] = (kk < 11) ? f2bfc(wc2(tpw, kk * 32 + kl * 8 + i, ntc * 16 + r)) : (unsigned short)0;
  } else if (gid < 90112) {
    int g = gid - 65536, fid = g >> 9, q = fid >> 3, wid = fid & 7;
    int t44 = wid + q * 8, nt = t44 >> 1, k = kl * 8 + i;
    Wfq[g] = (t44 < 44 && k < 20) ? f2bfc(rbf_w[k * NH + nt * 16 + r]) : (unsigned short)0;
  }
}

// T-element emitter: tv[i] = sum_m cf[m] * x1vec[m][i], packed to bf16x8.
template<int M>
__device__ __forceinline__ void emit_dot(unsigned short* dst, const unsigned short* x1,
                                         const int* offs, const float* cf) {
  us8v xv[M];
  #pragma unroll
  for (int m = 0; m < M; ++m) xv[m] = *(const us8v*)&x1[offs[m]];
  v8bf o;
  #pragma unroll
  for (int i = 0; i < 8; ++i) {
    float a = 0.f;
    #pragma unroll
    for (int m = 0; m < M; ++m) a = fmaf(cf[m], bf2f(xv[m][i]), a);
    o[i] = (__bf16)a;
  }
  *(us8v*)dst = __builtin_bit_cast(us8v, o);
}

// ---------------- T-slice builders ------------------------------------------
#define TSW(e, idx) ((idx) ^ (((e) & 7) << 3))

__device__ __forceinline__ void build0(unsigned short* Tb, const unsigned short* X1u,
                                       const float* RshF, int tid) {
  for (int it = tid; it < 32 * 28; it += BS) {
    int e = it / 28, ub = it - e * 28, u0 = ub * 8;
    const float* R = &RshF[e * 9];
    const unsigned short* x1 = &X1u[e * 480];
    unsigned short* dst = Tb + TSW(e, e * 384 + u0);
    if (u0 < 128) {
      float cf[1] = { PW0 * R[0] };
      int offs[1] = { u0 };
      emit_dot<1>(dst, x1, offs, cf);
    } else if (u0 < 192) {
      int m0 = u0 - 128;
      float cf[3] = { PW0 * C110 * R[1], PW0 * C110 * R[2], PW0 * C110 * R[3] };
      int offs[3] = { 128 + m0, 192 + m0, 256 + m0 };
      emit_dot<3>(dst, x1, offs, cf);
    } else {
      int m0 = u0 - 192;
      float cf[5] = { PW0 * C220 * R[4], PW0 * C220 * R[5], PW0 * C220 * R[6],
                      PW0 * C220 * R[7], PW0 * C220 * R[8] };
      int offs[5] = { 320 + m0, 352 + m0, 384 + m0, 416 + m0, 448 + m0 };
      emit_dot<5>(dst, x1, offs, cf);
    }
  }
}

template<int k>
__device__ __forceinline__ void build1(unsigned short* Tb, const unsigned short* X1u,
                                       const float* RshF, int tid) {
  for (int it = tid; it < 32 * 48; it += BS) {
    int e = it / 48, ub = it - e * 48, u0 = ub * 8;
    const float* R = &RshF[e * 9];
    const unsigned short* x1 = &X1u[e * 480];
    unsigned short* dst = Tb + TSW(e, e * 384 + u0);
    const float s = R[0], v0 = R[1], v1 = R[2], v2 = R[3];
    const float w0 = R[4], w1 = R[5], w2 = R[6], w3 = R[7], w4 = R[8];
    if (u0 < 128) {
      float cf[1] = { PW1 * C110 * R[1 + k] };
      int offs[1] = { u0 };
      emit_dot<1>(dst, x1, offs, cf);
    } else if (u0 < 192) {
      float cf[1] = { PW1 * C110 * s };
      int offs[1] = { 128 + k * 64 + (u0 - 128) };
      emit_dot<1>(dst, x1, offs, cf);
    } else if (u0 < 256) {
      constexpr int ka = (k + 1) % 3, kb = (k + 2) % 3;
      int m0 = u0 - 192;
      float cf[2] = { PW1 * C111 * R[1 + kb], -PW1 * C111 * R[1 + ka] };
      int offs[2] = { 128 + ka * 64 + m0, 128 + kb * 64 + m0 };
      emit_dot<2>(dst, x1, offs, cf);
    } else if (u0 < 320) {
      int m0 = u0 - 256;
      float cf[3];
      if constexpr (k == 0) { cf[0] = PW1*C11X*(-CA*w2 + CR*w4); cf[1] = PW1*C11X*CR*w0; cf[2] = PW1*C11X*CR*w3; }
      else if constexpr (k == 1) { cf[0] = PW1*C11X*CR*w0; cf[1] = PW1*C11X*(-CA*w2 - CR*w4); cf[2] = PW1*C11X*CR*w1; }
      else { cf[0] = PW1*C11X*CR*w3; cf[1] = PW1*C11X*CR*w1; cf[2] = PW1*C11X*2.f*CA*w2; }
      int offs[3] = { 128 + m0, 192 + m0, 256 + m0 };
      emit_dot<3>(dst, x1, offs, cf);
    } else if (u0 < 352) {
      int m0 = u0 - 320;
      if constexpr (k == 0) {
        float cf[4] = { PW1*C11X*CR*v1, PW1*C11X*(-CA*v0), PW1*C11X*CR*v2, PW1*C11X*CR*v0 };
        int offs[4] = { 320 + m0, 384 + m0, 416 + m0, 448 + m0 };
        emit_dot<4>(dst, x1, offs, cf);
      } else if constexpr (k == 1) {
        float cf[4] = { PW1*C11X*CR*v0, PW1*C11X*CR*v2, PW1*C11X*(-CA*v1), PW1*C11X*(-CR*v1) };
        int offs[4] = { 320 + m0, 352 + m0, 384 + m0, 448 + m0 };
        emit_dot<4>(dst, x1, offs, cf);
      } else {
        float cf[3] = { PW1*C11X*CR*v1, PW1*C11X*2.f*CA*v2, PW1*C11X*CR*v0 };
        int offs[3] = { 352 + m0, 384 + m0, 416 + m0 };
        emit_dot<3>(dst, x1, offs, cf);
      }
    } else {
      int m0 = u0 - 352;
      if constexpr (k == 0) {
        float cf[5] = { PW1*C221*0.5f*w3, PW1*C221*(S32*w2 + 0.5f*w4), PW1*C221*(-S32*w1),
                        PW1*C221*(-0.5f*w0), PW1*C221*(-0.5f*w1) };
        int offs[5] = { 320 + m0, 352 + m0, 384 + m0, 416 + m0, 448 + m0 };
        emit_dot<5>(dst, x1, offs, cf);
      } else if constexpr (k == 1) {
        float cf[5] = { PW1*C221*(-0.5f*w1), PW1*C221*0.5f*w0, PW1*C221*S32*w3,
                        PW1*C221*(-S32*w2 + 0.5f*w4), PW1*C221*(-0.5f*w3) };
        int offs[5] = { 320 + m0, 352 + m0, 384 + m0, 416 + m0, 448 + m0 };
        emit_dot<5>(dst, x1, offs, cf);
      } else {
        float cf[4] = { PW1*C221*(-w4), PW1*C221*(-0.5f*w3), PW1*C221*0.5f*w1, PW1*C221*w0 };
        int offs[4] = { 320 + m0, 352 + m0, 416 + m0, 448 + m0 };
        emit_dot<4>(dst, x1, offs, cf);
      }
    }
  }
}

template<int K>
__device__ __forceinline__ void build2(unsigned short* Tb, const unsigned short* X1u,
                                       const float* RshF, int tid) {
  for (int it = tid; it < 32 * 44; it += BS) {
    int e = it / 44, ub = it - e * 44, u0 = ub * 8;
    const float* R = &RshF[e * 9];
    const unsigned short* x1 = &X1u[e * 480];
    unsigned short* dst = Tb + TSW(e, e * 384 + u0);
    const float s = R[0], v0 = R[1], v1 = R[2], v2 = R[3];
    const float w0 = R[4], w1 = R[5], w2 = R[6], w3 = R[7], w4 = R[8];
    if (u0 < 128) {
      float cf[1] = { PW2 * C220 * R[4 + K] };
      int offs[1] = { u0 };
      emit_dot<1>(dst, x1, offs, cf);
    } else if (u0 < 192) {
      int m0 = u0 - 128;
      if constexpr (K == 0) {
        float cf[2] = { PW2*C11X*CR*v1, PW2*C11X*CR*v0 };
        int offs[2] = { 128 + m0, 192 + m0 };
        emit_dot<2>(dst, x1, offs, cf);
      } else if constexpr (K == 1) {
        float cf[2] = { PW2*C11X*CR*v2, PW2*C11X*CR*v1 };
        int offs[2] = { 192 + m0, 256 + m0 };
        emit_dot<2>(dst, x1, offs, cf);
      } else if constexpr (K == 2) {
        float cf[3] = { PW2*C11X*(-CA*v0), PW2*C11X*(-CA*v1), PW2*C11X*2.f*CA*v2 };
        int offs[3] = { 128 + m0, 192 + m0, 256 + m0 };
        emit_dot<3>(dst, x1, offs, cf);
      } else if constexpr (K == 3) {
        float cf[2] = { PW2*C11X*CR*v2, PW2*C11X*CR*v0 };
        int offs[2] = { 128 + m0, 256 + m0 };
        emit_dot<2>(dst, x1, offs, cf);
      } else {
        float cf[2] = { PW2*C11X*CR*v0, PW2*C11X*(-CR*v1) };
        int offs[2] = { 128 + m0, 192 + m0 };
        emit_dot<2>(dst, x1, offs, cf);
      }
    } else if (u0 < 256) {
      int m0 = u0 - 192;
      if constexpr (K == 2) {
        float cf[2] = { PW2*C221*S32*w1, PW2*C221*(-S32*w3) };
        int offs[2] = { 128 + m0, 192 + m0 };
        emit_dot<2>(dst, x1, offs, cf);
      } else {
        float cf[3];
        if constexpr (K == 0) { cf[0]=PW2*C221*(-0.5f*w3); cf[1]=PW2*C221*0.5f*w1; cf[2]=PW2*C221*w4; }
        else if constexpr (K == 1) { cf[0]=PW2*C221*(-S32*w2 - 0.5f*w4); cf[1]=PW2*C221*(-0.5f*w0); cf[2]=PW2*C221*0.5f*w3; }
        else if constexpr (K == 3) { cf[0]=PW2*C221*0.5f*w0; cf[1]=PW2*C221*(S32*w2 - 0.5f*w4); cf[2]=PW2*C221*(-0.5f*w1); }
        else { cf[0]=PW2*C221*0.5f*w1; cf[1]=PW2*C221*0.5f*w3; cf[2]=PW2*C221*(-w0); }
        int offs[3] = { 128 + m0, 192 + m0, 256 + m0 };
        emit_dot<3>(dst, x1, offs, cf);
      }
    } else if (u0 < 288) {
      int m0 = u0 - 256;
      float cf[1] = { PW2 * C220 * s };
      int offs[1] = { 320 + K * 32 + m0 };
      emit_dot<1>(dst, x1, offs, cf);
    } else if (u0 < 320) {
      int m0 = u0 - 288;
      if constexpr (K == 0) {
        float cf[3] = { PW2*C221*0.5f*v1, PW2*C221*(-0.5f*v0), PW2*C221*v2 };
        int offs[3] = { 352 + m0, 416 + m0, 448 + m0 };
        emit_dot<3>(dst, x1, offs, cf);
      } else if constexpr (K == 1) {
        float cf[4] = { PW2*C221*(-0.5f*v1), PW2*C221*(-S32*v0), PW2*C221*0.5f*v2, PW2*C221*(-0.5f*v0) };
        int offs[4] = { 320 + m0, 384 + m0, 416 + m0, 448 + m0 };
        emit_dot<4>(dst, x1, offs, cf);
      } else if constexpr (K == 2) {
        float cf[2] = { PW2*C221*S32*v0, PW2*C221*(-S32*v1) };
        int offs[2] = { 352 + m0, 416 + m0 };
        emit_dot<2>(dst, x1, offs, cf);
      } else if constexpr (K == 3) {
        float cf[4] = { PW2*C221*0.5f*v0, PW2*C221*(-0.5f*v2), PW2*C221*S32*v1, PW2*C221*(-0.5f*v1) };
        int offs[4] = { 320 + m0, 352 + m0, 384 + m0, 448 + m0 };
        emit_dot<4>(dst, x1, offs, cf);
      } else {
        float cf[3] = { PW2*C221*(-v2), PW2*C221*0.5f*v0, PW2*C221*0.5f*v1 };
        int offs[3] = { 320 + m0, 352 + m0, 416 + m0 };
        emit_dot<3>(dst, x1, offs, cf);
      }
    } else {
      int m0 = u0 - 320;
      if constexpr (K == 0) {
        float cf[4] = { PW2*C222*(-CA*w2), PW2*C222*HR*w3, PW2*C222*(-CA*w0), PW2*C222*HR*w1 };
        int offs[4] = { 320 + m0, 352 + m0, 384 + m0, 416 + m0 };
        emit_dot<4>(dst, x1, offs, cf);
      } else if constexpr (K == 4) {
        float cf[4] = { PW2*C222*(-HR*w1), PW2*C222*(-CA*w4), PW2*C222*HR*w3, PW2*C222*(-CA*w2) };
        int offs[4] = { 352 + m0, 384 + m0, 416 + m0, 448 + m0 };
        emit_dot<4>(dst, x1, offs, cf);
      } else {
        float cf[5];
        if constexpr (K == 1) { cf[0]=PW2*C222*HR*w3; cf[1]=PW2*C222*(HA*w2 - HR*w4); cf[2]=PW2*C222*HA*w1; cf[3]=PW2*C222*HR*w0; cf[4]=PW2*C222*(-HR*w1); }
        else if constexpr (K == 2) { cf[0]=PW2*C222*(-CA*w0); cf[1]=PW2*C222*HA*w1; cf[2]=PW2*C222*CA*w2; cf[3]=PW2*C222*HA*w3; cf[4]=PW2*C222*(-CA*w4); }
        else { cf[0]=PW2*C222*HR*w1; cf[1]=PW2*C222*HR*w0; cf[2]=PW2*C222*HA*w3; cf[3]=PW2*C222*(HA*w2 + HR*w4); cf[4]=PW2*C222*HR*w3; }
        int offs[5] = { 320 + m0, 352 + m0, 384 + m0, 416 + m0, 448 + m0 };
        emit_dot<5>(dst, x1, offs, cf);
      }
    }
  }
}

// ---------------- Fused TP kernel (dst-sorted, CHUNKED tile ranges) ---------
// Chunked assignment: all tiles touching a given dst row run in ONE block,
// sequentially -> no cross-block same-line atomic contention; RMW lines stay
// hot in the local XCD L2.
__global__ __launch_bounds__(BS, 4) void tp_fused_kernel(
    const float* __restrict__ rbf, const float* __restrict__ rsh,
    const int* __restrict__ es_dst, const int* __restrict__ es_src,
    const int* __restrict__ es_eid,
    const float* __restrict__ s_out, const float* __restrict__ sphT,
    const unsigned short* __restrict__ W0g, const unsigned short* __restrict__ W1g,
    const unsigned short* __restrict__ W2g, const unsigned short* __restrict__ Wfq,
    float* __restrict__ out0, float* __restrict__ out1T)
{
  __shared__ __align__(16) unsigned char smem[81408];
  unsigned short* Tb0 = (unsigned short*)smem;
  unsigned short* Tb1 = (unsigned short*)(smem + 24576);
  unsigned short* gateU = (unsigned short*)smem;
  unsigned short* rbfpadU = (unsigned short*)(smem + 24576);
  unsigned short* X1u = (unsigned short*)(smem + 49152);
  float* RshF = (float*)(smem + 79872);
  int* EdstS = (int*)(smem + 81024);
  int* EsrcS = (int*)(smem + 81152);
  int* EidS  = (int*)(smem + 81280);

  const int tid = threadIdx.x;
  const int wid = tid >> 6, lane = tid & 63;
  const int r = lane & 15, kl = lane >> 4;

  auto MFMA = [](v8bf a, v8bf b, f32x4 c) {
    return __builtin_amdgcn_mfma_f32_16x16x32_bf16(a, b, c, 0, 0, 0);
  };
  auto ldw = [&](const unsigned short* base, int fid) {
    return __builtin_bit_cast(v8bf, *(const us8v*)&base[fid * 512 + lane * 8]);
  };

  auto mfma_l0 = [&](const unsigned short* T) {
    f32x4 acc0 = {0.f, 0.f, 0.f, 0.f}, acc1 = {0.f, 0.f, 0.f, 0.f};
    #pragma unroll
    for (int kk = 0; kk < 7; ++kk) {
      v8bf b = ldw(W0g, kk * 8 + wid);
      us8v a0 = *(const us8v*)&T[TSW(r, r * 384 + kl * 8 + kk * 32)];
      us8v a1 = *(const us8v*)&T[TSW(r, (16 + r) * 384 + kl * 8 + kk * 32)];
      acc0 = MFMA(__builtin_bit_cast(v8bf, a0), b, acc0);
      acc1 = MFMA(__builtin_bit_cast(v8bf, a1), b, acc1);
    }
    int col = wid * 16 + r;
    #pragma unroll
    for (int j = 0; j < 4; ++j) {
      unsafeAtomicAdd(&out1T[(long)EdstS[kl * 4 + j] * SD + col], acc0[j]);
      unsafeAtomicAdd(&out1T[(long)EdstS[16 + kl * 4 + j] * SD + col], acc1[j]);
    }
  };

  auto mfma_l1 = [&](const unsigned short* T, int k) {
    const int mt = wid >> 2, nt = wid & 3;
    f32x4 acc = {0.f, 0.f, 0.f, 0.f};
    #pragma unroll
    for (int kk = 0; kk < 12; ++kk) {
      v8bf b = ldw(W1g, kk * 4 + nt);
      us8v a = *(const us8v*)&T[TSW(r, (mt * 16 + r) * 384 + kl * 8 + kk * 32)];
      acc = MFMA(__builtin_bit_cast(v8bf, a), b, acc);
    }
    int col = 128 + k * 64 + nt * 16 + r;
    #pragma unroll
    for (int j = 0; j < 4; ++j)
      unsafeAtomicAdd(&out1T[(long)EdstS[mt * 16 + kl * 4 + j] * SD + col], acc[j]);
  };

  auto mfma_l2 = [&](const unsigned short* T, int K) {
    const int kh = wid >> 2, mt = (wid >> 1) & 1, ntc = wid & 1;
    f32x4 acc = {0.f, 0.f, 0.f, 0.f};
    #pragma unroll
    for (int q = 0; q < 6; ++q) {
      if (kh == 0 || q < 5) {
        v8bf b = ldw(W2g, q * 4 + kh * 2 + ntc);
        us8v a = *(const us8v*)&T[TSW(r, (mt * 16 + r) * 384 + kh * 192 + q * 32 + kl * 8)];
        acc = MFMA(__builtin_bit_cast(v8bf, a), b, acc);
      }
    }
    int col = 320 + K * 32 + ntc * 16 + r;
    #pragma unroll
    for (int j = 0; j < 4; ++j)
      unsafeAtomicAdd(&out1T[(long)EdstS[mt * 16 + kl * 4 + j] * SD + col], acc[j]);
  };

  // CHUNKED range: block b owns sorted tiles [NTILE*b/G, NTILE*(b+1)/G)
  const int tbeg = (int)(((long)NTILE * blockIdx.x) / gridDim.x);
  const int tend = (int)(((long)NTILE * (blockIdx.x + 1)) / gridDim.x);
  for (int tile = tbeg; tile < tend; ++tile) {
    const int e0 = tile * 32;
    // ---- stage edge triples (sorted by dst) ----
    for (int i = tid; i < 32; i += BS) {
      EdstS[i] = es_dst[e0 + i]; EsrcS[i] = es_src[e0 + i]; EidS[i] = es_eid[e0 + i];
    }
    __syncthreads();
    for (int i = tid; i < 288; i += BS) RshF[i] = rsh[(long)EidS[i / 9] * 9 + i % 9];
    for (int i = tid; i < 1024; i += BS) {
      int e = i >> 5, b = i & 31;
      rbfpadU[e * 40 + b] = (b < 20) ? f2bfc(rbf[(long)EidS[e] * NB + b]) : (unsigned short)0;
    }
    __syncthreads();
    // ---- filt MFMA -> gate (bf16 LDS) + scalar msg (atomics) ----
    {
      us8v ra0 = *(const us8v*)&rbfpadU[r * 40 + kl * 8];
      us8v ra1 = *(const us8v*)&rbfpadU[(16 + r) * 40 + kl * 8];
      v8bf av0 = __builtin_bit_cast(v8bf, ra0);
      v8bf av1 = __builtin_bit_cast(v8bf, ra1);
      #pragma unroll
      for (int q = 0; q < 6; ++q) {
        int t44 = wid + q * 8;
        if (t44 < 44) {
          int mt = t44 & 1, nt = t44 >> 1;
          v8bf b = ldw(Wfq, q * 8 + wid);
          f32x4 acc = {0.f, 0.f, 0.f, 0.f};
          acc = MFMA(mt ? av1 : av0, b, acc);
          int gi = nt * 16 + r;
          #pragma unroll
          for (int j = 0; j < 4; ++j) {
            int e = mt * 16 + kl * 4 + j;
            float so = s_out[(long)EsrcS[e] * NH + gi];
            float val = acc[j] * so;
            if (nt < 14) gateU[e * 232 + gi] = f2bfc(val);
            else unsafeAtomicAdd(&out0[(long)EdstS[e] * ND + (gi - 224)], val);
          }
        }
      }
    }
    __syncthreads();
    // ---- X1 build (all-vector loads from component-major sphT) ----
    for (int it = tid; it < 1920; it += BS) {
      int e = it / 60, cb = it - e * 60, c0 = cb * 8;
      long srow = (long)EsrcS[e] * SD;
      int gidx = (c0 < 128) ? c0 : (c0 < 320) ? 128 + (c0 & 63) : 192 + (c0 & 31);
      us8v gv = *(const us8v*)&gateU[e * 232 + gidx];
      const float4 sa = *(const float4*)&sphT[srow + c0];
      const float4 sb = *(const float4*)&sphT[srow + c0 + 4];
      float sv[8] = {sa.x, sa.y, sa.z, sa.w, sb.x, sb.y, sb.z, sb.w};
      v8bf o;
      #pragma unroll
      for (int i = 0; i < 8; ++i) o[i] = (__bf16)(sv[i] * bf2f(gv[i]));
      *(us8v*)&X1u[e * 480 + c0] = __builtin_bit_cast(us8v, o);
    }
    __syncthreads();
    // ---- 9 phases, double-buffered T, per-phase flush ----
    build0(Tb0, X1u, RshF, tid); __syncthreads();
    build1<0>(Tb1, X1u, RshF, tid); mfma_l0(Tb0); __syncthreads();
    build1<1>(Tb0, X1u, RshF, tid); mfma_l1(Tb1, 0); __syncthreads();
    build1<2>(Tb1, X1u, RshF, tid); mfma_l1(Tb0, 1); __syncthreads();
    build2<0>(Tb0, X1u, RshF, tid); mfma_l1(Tb1, 2); __syncthreads();
    build2<1>(Tb1, X1u, RshF, tid); mfma_l2(Tb0, 0); __syncthreads();
    build2<2>(Tb0, X1u, RshF, tid); mfma_l2(Tb1, 1); __syncthreads();
    build2<3>(Tb1, X1u, RshF, tid); mfma_l2(Tb0, 2); __syncthreads();
    build2<4>(Tb0, X1u, RshF, tid); mfma_l2(Tb1, 3); __syncthreads();
    mfma_l2(Tb0, 4); __syncthreads();
  }
}

// ---------------- Merge: out1 = sphT[tT] + out1T[tT]  (un-transpose) --------
__global__ __launch_bounds__(512) void merge_kernel(
    const float* __restrict__ sphT, const float* __restrict__ out1T,
    float* __restrict__ out1)
{
  const int n = blockIdx.x, t = threadIdx.x;
  if (t < SD) {
    int tT = t2tT(t);
    out1[(long)n * SD + t] = sphT[(long)n * SD + tT] + out1T[(long)n * SD + tT];
  }
}

extern "C" void kernel_launch(void* const* d_in, const int* in_sizes, int n_in,
                              void* d_out, int out_size, void* d_ws, size_t ws_size,
                              hipStream_t stream)
{
  const float* xs   = (const float*)d_in[0];
  const float* xsph = (const float*)d_in[1];
  const float* rbf  = (const float*)d_in[2];
  const float* rsh  = (const float*)d_in[3];
  const int*   ei   = (const int*)d_in[4];
  const float* lnw  = (const float*)d_in[5];
  const float* lnb  = (const float*)d_in[6];
  const float* o3w  = (const float*)d_in[7];
  const float* o3b  = (const float*)d_in[8];
  const float* w1   = (const float*)d_in[9];
  const float* b1   = (const float*)d_in[10];
  const float* w2   = (const float*)d_in[11];
  const float* b2   = (const float*)d_in[12];
  const float* rbfw = (const float*)d_in[13];
  const float* tpw  = (const float*)d_in[14];

  float* out0 = (float*)d_out;
  float* out1 = out0 + (size_t)NN * ND;

  float* ws      = (float*)d_ws;
  float* s_in    = ws;                              // 10000*128
  float* sphT    = ws + (size_t)NN * ND;            // 10000*480 (component-major)
  float* s_out   = ws + (size_t)NN * (ND + SD);     // 10000*352
  float* out1T   = ws + (size_t)NN * (ND + SD + NH);// 10000*480
  unsigned short* wbase = (unsigned short*)(ws + (size_t)NN * (ND + 2 * SD + NH));
  unsigned short* W0g = wbase;              // 28672
  unsigned short* W1g = wbase + 28672;      // 24576
  unsigned short* W2g = wbase + 53248;      // 12288
  unsigned short* Wfq = wbase + 65536;      // 24576  (total 90112 ush)
  int* ibase  = (int*)(wbase + 90112);
  int* cnt    = ibase;               // 10000
  int* cursor = ibase + 10000;       // 10000
  int* es_dst = ibase + 20000;       // 100000
  int* es_src = ibase + 120000;      // 100000
  int* es_eid = ibase + 220000;      // 100000

  hipMemsetAsync(out1T, 0, (size_t)NN * SD * sizeof(float), stream);
  hipMemsetAsync(cnt, 0, (size_t)NN * sizeof(int), stream);
  sort_hist<<<(NE + 255) / 256, 256, 0, stream>>>(ei, cnt);
  sort_scan<<<1, 1024, 0, stream>>>(cnt, cursor);
  sort_scatter<<<(NE + 255) / 256, 256, 0, stream>>>(ei, cursor, es_dst, es_src, es_eid);
  prep_w_kernel<<<352, 256, 0, stream>>>(tpw, rbfw, W0g, W1g, W2g, Wfq);
  node_ln_kernel<<<NN, 128, 0, stream>>>(xs, xsph, lnw, lnb, o3w, o3b, s_in, sphT, out0);
  mlp_kernel<<<NN / NPB, 256, 0, stream>>>(s_in, w1, b1, w2, b2, s_out);
  tp_fused_kernel<<<512, BS, 0, stream>>>(rbf, rsh, es_dst, es_src, es_eid, s_out, sphT,
                                          W0g, W1g, W2g, Wfq, out0, out1T);
  merge_kernel<<<NN, 512, 0, stream>>>(sphT, out1T, out1);
}

// Round 8
// 699.177 us; speedup vs baseline: 1.5541x; 1.5541x over previous
//
#include <hip/hip_runtime.h>

#define NN 10000
#define NE 100000
#define ND 128
#define NB 20
#define NIR 224
#define NH 352
#define SD 480
#define BS 512

// CG / normalization constants (verified in R1/R2)
#define CR   0.70710678118654752f
#define CA   0.40824829046386302f
#define HA   0.20412414523193151f
#define HR   0.35355339059327376f
#define C110 0.57735026918962576f
#define C220 0.44721359549995794f
#define C111 0.40824829046386302f
#define C11X 0.44721359549995794f
#define C221 0.36514837167011074f
#define C222 0.58554004376912270f
#define S32  0.86602540378443865f
#define PW0  0.066815310478106094f
#define PW1  0.088388347648318447f
#define PW2  0.11918321088232916f

typedef __bf16 v8bf __attribute__((ext_vector_type(8)));
typedef unsigned short us8v __attribute__((ext_vector_type(8)));
typedef float f32x4 __attribute__((ext_vector_type(4)));

__device__ __forceinline__ unsigned short f2bfc(float f) {
  __bf16 h = (__bf16)f;
  return __builtin_bit_cast(unsigned short, h);
}
__device__ __forceinline__ float bf2f(unsigned short h) {
  unsigned int u = ((unsigned int)h) << 16;
  return __builtin_bit_cast(float, u);
}

__device__ __forceinline__ float warpReduceSum(float v) {
  #pragma unroll
  for (int off = 32; off > 0; off >>= 1) v += __shfl_down(v, off, 64);
  return v;
}

// component-major index mapping for spherical rows
__device__ __forceinline__ int t2tT(int t) {
  if (t < 128) return t;
  if (t < 320) { int c = t - 128; return 128 + (c % 3) * 64 + c / 3; }
  int c = t - 320; return 320 + (c % 5) * 32 + c / 5;
}

// ---------------- Sort kernels: counting sort of edges by dst (gather only) --
__global__ __launch_bounds__(256) void sort_hist(const int* __restrict__ ei, int* __restrict__ cnt) {
  int e = blockIdx.x * 256 + threadIdx.x;
  if (e < NE) atomicAdd(&cnt[ei[e]], 1);
}

__global__ __launch_bounds__(1024) void sort_scan(const int* __restrict__ cnt, int* __restrict__ cursor) {
  __shared__ int part[1024];
  const int t = threadIdx.x;
  int loc[10]; int s = 0;
  #pragma unroll
  for (int j = 0; j < 10; ++j) { int idx = t * 10 + j; int v = (idx < NN) ? cnt[idx] : 0; loc[j] = s; s += v; }
  part[t] = s; __syncthreads();
  for (int d = 1; d < 1024; d <<= 1) {
    int v = (t >= d) ? part[t - d] : 0; __syncthreads();
    part[t] += v; __syncthreads();
  }
  int off = part[t] - s;
  #pragma unroll
  for (int j = 0; j < 10; ++j) { int idx = t * 10 + j; if (idx < NN) cursor[idx] = off + loc[j]; }
}

__global__ __launch_bounds__(256) void sort_scatter(
    const int* __restrict__ ei, int* __restrict__ cursor,
    int* __restrict__ es_eid) {
  int e = blockIdx.x * 256 + threadIdx.x;
  if (e < NE) {
    int d = ei[e];
    int pos = atomicAdd(&cursor[d], 1);
    es_eid[pos] = e;
  }
}

// ---------------- Kernel 1: scalar LN + O3 LN (writes sphT component-major) --
__global__ __launch_bounds__(128) void node_ln_kernel(
    const float* __restrict__ xs, const float* __restrict__ xsph,
    const float* __restrict__ lnw, const float* __restrict__ lnb,
    const float* __restrict__ o3w, const float* __restrict__ o3b,
    float* __restrict__ s_in, float* __restrict__ sphT,
    float* __restrict__ out0)
{
  const int n = blockIdx.x, t = threadIdx.x;
  __shared__ float red[4];

  auto reduce2 = [&](float a, float b) {
    a = warpReduceSum(a); b = warpReduceSum(b);
    if ((t & 63) == 0) { red[(t >> 6) * 2] = a; red[(t >> 6) * 2 + 1] = b; }
    __syncthreads();
    float ra = red[0] + red[2], rb = red[1] + red[3];
    __syncthreads();
    return make_float2(ra, rb);
  };

  float x = xs[n * ND + t];
  float2 sr = reduce2(x, x * x);
  float mu = sr.x * (1.f / ND);
  float var = sr.y * (1.f / ND) - mu * mu;
  float y = (x - mu) * rsqrtf(var + 1e-5f) * lnw[t] + lnb[t];
  s_in[n * ND + t] = y; out0[n * ND + t] = y;

  float f = xsph[n * SD + t];
  float2 r0 = reduce2(f, f * f);
  float m0 = r0.x * (1.f / 128.f);
  float nrm0 = r0.y * (1.f / 128.f) - m0 * m0;
  float y0 = (f - m0) * rsqrtf(nrm0 + 1e-5f) * o3w[t] + o3b[t];
  sphT[n * SD + t] = y0;

  float f1a = xsph[n * SD + 128 + t];
  float f1b = (t < 64) ? xsph[n * SD + 256 + t] : 0.f;
  float2 r1 = reduce2(f1a * f1a + f1b * f1b, 0.f);
  float rs1 = rsqrtf(r1.x * (1.f / 192.f) + 1e-5f);
  sphT[n * SD + t2tT(128 + t)] = f1a * rs1 * o3w[128 + t / 3];
  if (t < 64)
    sphT[n * SD + t2tT(256 + t)] = f1b * rs1 * o3w[128 + (128 + t) / 3];

  float f2a = xsph[n * SD + 320 + t];
  float f2b = (t < 32) ? xsph[n * SD + 448 + t] : 0.f;
  float2 r2 = reduce2(f2a * f2a + f2b * f2b, 0.f);
  float rs2 = rsqrtf(r2.x * (1.f / 160.f) + 1e-5f);
  sphT[n * SD + t2tT(320 + t)] = f2a * rs2 * o3w[192 + t / 5];
  if (t < 32)
    sphT[n * SD + t2tT(448 + t)] = f2b * rs2 * o3w[192 + (128 + t) / 5];
}

// ---------------- Kernel 2: node MLP (unchanged, verified) ------------------
#define NPB 8
__global__ __launch_bounds__(256) void mlp_kernel(
    const float* __restrict__ s_in, const float* __restrict__ w1,
    const float* __restrict__ b1, const float* __restrict__ w2,
    const float* __restrict__ b2, float* __restrict__ s_out)
{
  __shared__ float sIn[NPB][ND];
  __shared__ float sH[NPB][ND];
  const int t = threadIdx.x;
  const int n0 = blockIdx.x * NPB;
  for (int i = t; i < NPB * ND; i += 256) sIn[i >> 7][i & 127] = s_in[n0 * ND + i];
  __syncthreads();
  {
    const int j = t & 127, g = t >> 7;
    float acc[4] = {0.f, 0.f, 0.f, 0.f};
    for (int k = 0; k < ND; ++k) {
      float w = w1[k * ND + j];
      #pragma unroll
      for (int i = 0; i < 4; ++i) acc[i] = fmaf(sIn[g + 2 * i][k], w, acc[i]);
    }
    #pragma unroll
    for (int i = 0; i < 4; ++i) {
      float z = acc[i] + b1[j];
      sH[g + 2 * i][j] = z / (1.f + __expf(-z));
    }
  }
  __syncthreads();
  for (int jb = 0; jb < 2; ++jb) {
    int j = jb * 256 + t;
    if (j < NH) {
      float acc[NPB];
      #pragma unroll
      for (int i = 0; i < NPB; ++i) acc[i] = b2[j];
      for (int k = 0; k < ND; ++k) {
        float w = w2[k * NH + j];
        #pragma unroll
        for (int i = 0; i < NPB; ++i) acc[i] = fmaf(sH[i][k], w, acc[i]);
      }
      #pragma unroll
      for (int i = 0; i < NPB; ++i) s_out[(n0 + i) * NH + j] = acc[i];
    }
  }
}

// ---------------- W element fetchers (tpw fp32 layout, verified offsets) ----
__device__ __forceinline__ float wc0(const float* w, int u, int j) {
  int off = (u < 128) ? u * 128 : (u < 192) ? 16384 + (u - 128) * 128 : 24576 + (u - 192) * 128;
  return w[off + j];
}
__device__ __forceinline__ float wc1(const float* w, int u, int j) {
  int off = (u < 128) ? 28672 + u * 64 : (u < 192) ? 36864 + (u - 128) * 64
          : (u < 256) ? 40960 + (u - 192) * 64 : (u < 320) ? 45056 + (u - 256) * 64
          : (u < 352) ? 49152 + (u - 320) * 64 : 51200 + (u - 352) * 64;
  return w[off + j];
}
__device__ __forceinline__ float wc2(const float* w, int u, int j) {
  int off = (u < 128) ? 53248 + u * 32 : (u < 192) ? 57344 + (u - 128) * 32
          : (u < 256) ? 59392 + (u - 192) * 32 : (u < 288) ? 61440 + (u - 256) * 32
          : (u < 320) ? 62464 + (u - 288) * 32 : 63488 + (u - 320) * 32;
  return w[off + j];
}

// ---------------- Prep kernel: pre-swizzle W into bf16 fragment layout ------
__global__ __launch_bounds__(256) void prep_w_kernel(
    const float* __restrict__ tpw, const float* __restrict__ rbf_w,
    unsigned short* __restrict__ W0g, unsigned short* __restrict__ W1g,
    unsigned short* __restrict__ W2g, unsigned short* __restrict__ Wfq)
{
  int gid = blockIdx.x * 256 + threadIdx.x;
  int i = gid & 7, lane = (gid >> 3) & 63;
  int r = lane & 15, kl = lane >> 4;
  if (gid < 28672) {
    int fid = gid >> 9, kk = fid >> 3, wid = fid & 7;
    W0g[gid] = f2bfc(wc0(tpw, kk * 32 + kl * 8 + i, wid * 16 + r));
  } else if (gid < 53248) {
    int g = gid - 28672, fid = g >> 9, kk = fid >> 2, nt = fid & 3;
    W1g[g] = f2bfc(wc1(tpw, kk * 32 + kl * 8 + i, nt * 16 + r));
  } else if (gid < 65536) {
    int g = gid - 53248, fid = g >> 9, q = fid >> 2, kh = (fid >> 1) & 1, ntc = fid & 1;
    int kk = kh * 6 + q;
    W2g[g] = (kk < 11) ? f2bfc(wc2(tpw, kk * 32 + kl * 8 + i, ntc * 16 + r)) : (unsigned short)0;
  } else if (gid < 90112) {
    int g = gid - 65536, fid = g >> 9, q = fid >> 3, wid = fid & 7;
    int t44 = wid + q * 8, nt = t44 >> 1, k = kl * 8 + i;
    Wfq[g] = (t44 < 44 && k < 20) ? f2bfc(rbf_w[k * NH + nt * 16 + r]) : (unsigned short)0;
  }
}

// T-element emitter: tv[i] = sum_m cf[m] * x1vec[m][i], packed to bf16x8.
template<int M>
__device__ __forceinline__ void emit_dot(unsigned short* dst, const unsigned short* x1,
                                         const int* offs, const float* cf) {
  us8v xv[M];
  #pragma unroll
  for (int m = 0; m < M; ++m) xv[m] = *(const us8v*)&x1[offs[m]];
  v8bf o;
  #pragma unroll
  for (int i = 0; i < 8; ++i) {
    float a = 0.f;
    #pragma unroll
    for (int m = 0; m < M; ++m) a = fmaf(cf[m], bf2f(xv[m][i]), a);
    o[i] = (__bf16)a;
  }
  *(us8v*)dst = __builtin_bit_cast(us8v, o);
}

// ---------------- T-slice builders ------------------------------------------
#define TSW(e, idx) ((idx) ^ (((e) & 7) << 3))

__device__ __forceinline__ void build0(unsigned short* Tb, const unsigned short* X1u,
                                       const float* RshF, int tid) {
  for (int it = tid; it < 32 * 28; it += BS) {
    int e = it / 28, ub = it - e * 28, u0 = ub * 8;
    const float* R = &RshF[e * 9];
    const unsigned short* x1 = &X1u[e * 480];
    unsigned short* dst = Tb + TSW(e, e * 384 + u0);
    if (u0 < 128) {
      float cf[1] = { PW0 * R[0] };
      int offs[1] = { u0 };
      emit_dot<1>(dst, x1, offs, cf);
    } else if (u0 < 192) {
      int m0 = u0 - 128;
      float cf[3] = { PW0 * C110 * R[1], PW0 * C110 * R[2], PW0 * C110 * R[3] };
      int offs[3] = { 128 + m0, 192 + m0, 256 + m0 };
      emit_dot<3>(dst, x1, offs, cf);
    } else {
      int m0 = u0 - 192;
      float cf[5] = { PW0 * C220 * R[4], PW0 * C220 * R[5], PW0 * C220 * R[6],
                      PW0 * C220 * R[7], PW0 * C220 * R[8] };
      int offs[5] = { 320 + m0, 352 + m0, 384 + m0, 416 + m0, 448 + m0 };
      emit_dot<5>(dst, x1, offs, cf);
    }
  }
}

template<int k>
__device__ __forceinline__ void build1(unsigned short* Tb, const unsigned short* X1u,
                                       const float* RshF, int tid) {
  for (int it = tid; it < 32 * 48; it += BS) {
    int e = it / 48, ub = it - e * 48, u0 = ub * 8;
    const float* R = &RshF[e * 9];
    const unsigned short* x1 = &X1u[e * 480];
    unsigned short* dst = Tb + TSW(e, e * 384 + u0);
    const float s = R[0], v0 = R[1], v1 = R[2], v2 = R[3];
    const float w0 = R[4], w1 = R[5], w2 = R[6], w3 = R[7], w4 = R[8];
    if (u0 < 128) {
      float cf[1] = { PW1 * C110 * R[1 + k] };
      int offs[1] = { u0 };
      emit_dot<1>(dst, x1, offs, cf);
    } else if (u0 < 192) {
      float cf[1] = { PW1 * C110 * s };
      int offs[1] = { 128 + k * 64 + (u0 - 128) };
      emit_dot<1>(dst, x1, offs, cf);
    } else if (u0 < 256) {
      constexpr int ka = (k + 1) % 3, kb = (k + 2) % 3;
      int m0 = u0 - 192;
      float cf[2] = { PW1 * C111 * R[1 + kb], -PW1 * C111 * R[1 + ka] };
      int offs[2] = { 128 + ka * 64 + m0, 128 + kb * 64 + m0 };
      emit_dot<2>(dst, x1, offs, cf);
    } else if (u0 < 320) {
      int m0 = u0 - 256;
      float cf[3];
      if constexpr (k == 0) { cf[0] = PW1*C11X*(-CA*w2 + CR*w4); cf[1] = PW1*C11X*CR*w0; cf[2] = PW1*C11X*CR*w3; }
      else if constexpr (k == 1) { cf[0] = PW1*C11X*CR*w0; cf[1] = PW1*C11X*(-CA*w2 - CR*w4); cf[2] = PW1*C11X*CR*w1; }
      else { cf[0] = PW1*C11X*CR*w3; cf[1] = PW1*C11X*CR*w1; cf[2] = PW1*C11X*2.f*CA*w2; }
      int offs[3] = { 128 + m0, 192 + m0, 256 + m0 };
      emit_dot<3>(dst, x1, offs, cf);
    } else if (u0 < 352) {
      int m0 = u0 - 320;
      if constexpr (k == 0) {
        float cf[4] = { PW1*C11X*CR*v1, PW1*C11X*(-CA*v0), PW1*C11X*CR*v2, PW1*C11X*CR*v0 };
        int offs[4] = { 320 + m0, 384 + m0, 416 + m0, 448 + m0 };
        emit_dot<4>(dst, x1, offs, cf);
      } else if constexpr (k == 1) {
        float cf[4] = { PW1*C11X*CR*v0, PW1*C11X*CR*v2, PW1*C11X*(-CA*v1), PW1*C11X*(-CR*v1) };
        int offs[4] = { 320 + m0, 352 + m0, 384 + m0, 448 + m0 };
        emit_dot<4>(dst, x1, offs, cf);
      } else {
        float cf[3] = { PW1*C11X*CR*v1, PW1*C11X*2.f*CA*v2, PW1*C11X*CR*v0 };
        int offs[3] = { 352 + m0, 384 + m0, 416 + m0 };
        emit_dot<3>(dst, x1, offs, cf);
      }
    } else {
      int m0 = u0 - 352;
      if constexpr (k == 0) {
        float cf[5] = { PW1*C221*0.5f*w3, PW1*C221*(S32*w2 + 0.5f*w4), PW1*C221*(-S32*w1),
                        PW1*C221*(-0.5f*w0), PW1*C221*(-0.5f*w1) };
        int offs[5] = { 320 + m0, 352 + m0, 384 + m0, 416 + m0, 448 + m0 };
        emit_dot<5>(dst, x1, offs, cf);
      } else if constexpr (k == 1) {
        float cf[5] = { PW1*C221*(-0.5f*w1), PW1*C221*0.5f*w0, PW1*C221*S32*w3,
                        PW1*C221*(-S32*w2 + 0.5f*w4), PW1*C221*(-0.5f*w3) };
        int offs[5] = { 320 + m0, 352 + m0, 384 + m0, 416 + m0, 448 + m0 };
        emit_dot<5>(dst, x1, offs, cf);
      } else {
        float cf[4] = { PW1*C221*(-w4), PW1*C221*(-0.5f*w3), PW1*C221*0.5f*w1, PW1*C221*w0 };
        int offs[4] = { 320 + m0, 352 + m0, 416 + m0, 448 + m0 };
        emit_dot<4>(dst, x1, offs, cf);
      }
    }
  }
}

template<int K>
__device__ __forceinline__ void build2(unsigned short* Tb, const unsigned short* X1u,
                                       const float* RshF, int tid) {
  for (int it = tid; it < 32 * 44; it += BS) {
    int e = it / 44, ub = it - e * 44, u0 = ub * 8;
    const float* R = &RshF[e * 9];
    const unsigned short* x1 = &X1u[e * 480];
    unsigned short* dst = Tb + TSW(e, e * 384 + u0);
    const float s = R[0], v0 = R[1], v1 = R[2], v2 = R[3];
    const float w0 = R[4], w1 = R[5], w2 = R[6], w3 = R[7], w4 = R[8];
    if (u0 < 128) {
      float cf[1] = { PW2 * C220 * R[4 + K] };
      int offs[1] = { u0 };
      emit_dot<1>(dst, x1, offs, cf);
    } else if (u0 < 192) {
      int m0 = u0 - 128;
      if constexpr (K == 0) {
        float cf[2] = { PW2*C11X*CR*v1, PW2*C11X*CR*v0 };
        int offs[2] = { 128 + m0, 192 + m0 };
        emit_dot<2>(dst, x1, offs, cf);
      } else if constexpr (K == 1) {
        float cf[2] = { PW2*C11X*CR*v2, PW2*C11X*CR*v1 };
        int offs[2] = { 192 + m0, 256 + m0 };
        emit_dot<2>(dst, x1, offs, cf);
      } else if constexpr (K == 2) {
        float cf[3] = { PW2*C11X*(-CA*v0), PW2*C11X*(-CA*v1), PW2*C11X*2.f*CA*v2 };
        int offs[3] = { 128 + m0, 192 + m0, 256 + m0 };
        emit_dot<3>(dst, x1, offs, cf);
      } else if constexpr (K == 3) {
        float cf[2] = { PW2*C11X*CR*v2, PW2*C11X*CR*v0 };
        int offs[2] = { 128 + m0, 256 + m0 };
        emit_dot<2>(dst, x1, offs, cf);
      } else {
        float cf[2] = { PW2*C11X*CR*v0, PW2*C11X*(-CR*v1) };
        int offs[2] = { 128 + m0, 192 + m0 };
        emit_dot<2>(dst, x1, offs, cf);
      }
    } else if (u0 < 256) {
      int m0 = u0 - 192;
      if constexpr (K == 2) {
        float cf[2] = { PW2*C221*S32*w1, PW2*C221*(-S32*w3) };
        int offs[2] = { 128 + m0, 192 + m0 };
        emit_dot<2>(dst, x1, offs, cf);
      } else {
        float cf[3];
        if constexpr (K == 0) { cf[0]=PW2*C221*(-0.5f*w3); cf[1]=PW2*C221*0.5f*w1; cf[2]=PW2*C221*w4; }
        else if constexpr (K == 1) { cf[0]=PW2*C221*(-S32*w2 - 0.5f*w4); cf[1]=PW2*C221*(-0.5f*w0); cf[2]=PW2*C221*0.5f*w3; }
        else if constexpr (K == 3) { cf[0]=PW2*C221*0.5f*w0; cf[1]=PW2*C221*(S32*w2 - 0.5f*w4); cf[2]=PW2*C221*(-0.5f*w1); }
        else { cf[0]=PW2*C221*0.5f*w1; cf[1]=PW2*C221*0.5f*w3; cf[2]=PW2*C221*(-w0); }
        int offs[3] = { 128 + m0, 192 + m0, 256 + m0 };
        emit_dot<3>(dst, x1, offs, cf);
      }
    } else if (u0 < 288) {
      int m0 = u0 - 256;
      float cf[1] = { PW2 * C220 * s };
      int offs[1] = { 320 + K * 32 + m0 };
      emit_dot<1>(dst, x1, offs, cf);
    } else if (u0 < 320) {
      int m0 = u0 - 288;
      if constexpr (K == 0) {
        float cf[3] = { PW2*C221*0.5f*v1, PW2*C221*(-0.5f*v0), PW2*C221*v2 };
        int offs[3] = { 352 + m0, 416 + m0, 448 + m0 };
        emit_dot<3>(dst, x1, offs, cf);
      } else if constexpr (K == 1) {
        float cf[4] = { PW2*C221*(-0.5f*v1), PW2*C221*(-S32*v0), PW2*C221*0.5f*v2, PW2*C221*(-0.5f*v0) };
        int offs[4] = { 320 + m0, 384 + m0, 416 + m0, 448 + m0 };
        emit_dot<4>(dst, x1, offs, cf);
      } else if constexpr (K == 2) {
        float cf[2] = { PW2*C221*S32*v0, PW2*C221*(-S32*v1) };
        int offs[2] = { 352 + m0, 416 + m0 };
        emit_dot<2>(dst, x1, offs, cf);
      } else if constexpr (K == 3) {
        float cf[4] = { PW2*C221*0.5f*v0, PW2*C221*(-0.5f*v2), PW2*C221*S32*v1, PW2*C221*(-0.5f*v1) };
        int offs[4] = { 320 + m0, 352 + m0, 384 + m0, 448 + m0 };
        emit_dot<4>(dst, x1, offs, cf);
      } else {
        float cf[3] = { PW2*C221*(-v2), PW2*C221*0.5f*v0, PW2*C221*0.5f*v1 };
        int offs[3] = { 320 + m0, 352 + m0, 416 + m0 };
        emit_dot<3>(dst, x1, offs, cf);
      }
    } else {
      int m0 = u0 - 320;
      if constexpr (K == 0) {
        float cf[4] = { PW2*C222*(-CA*w2), PW2*C222*HR*w3, PW2*C222*(-CA*w0), PW2*C222*HR*w1 };
        int offs[4] = { 320 + m0, 352 + m0, 384 + m0, 416 + m0 };
        emit_dot<4>(dst, x1, offs, cf);
      } else if constexpr (K == 4) {
        float cf[4] = { PW2*C222*(-HR*w1), PW2*C222*(-CA*w4), PW2*C222*HR*w3, PW2*C222*(-CA*w2) };
        int offs[4] = { 352 + m0, 384 + m0, 416 + m0, 448 + m0 };
        emit_dot<4>(dst, x1, offs, cf);
      } else {
        float cf[5];
        if constexpr (K == 1) { cf[0]=PW2*C222*HR*w3; cf[1]=PW2*C222*(HA*w2 - HR*w4); cf[2]=PW2*C222*HA*w1; cf[3]=PW2*C222*HR*w0; cf[4]=PW2*C222*(-HR*w1); }
        else if constexpr (K == 2) { cf[0]=PW2*C222*(-CA*w0); cf[1]=PW2*C222*HA*w1; cf[2]=PW2*C222*CA*w2; cf[3]=PW2*C222*HA*w3; cf[4]=PW2*C222*(-CA*w4); }
        else { cf[0]=PW2*C222*HR*w1; cf[1]=PW2*C222*HR*w0; cf[2]=PW2*C222*HA*w3; cf[3]=PW2*C222*(HA*w2 + HR*w4); cf[4]=PW2*C222*HR*w3; }
        int offs[5] = { 320 + m0, 352 + m0, 384 + m0, 416 + m0, 448 + m0 };
        emit_dot<5>(dst, x1, offs, cf);
      }
    }
  }
}

// ---------------- Fused TP kernel (R4 structure, dense bf16 msgT stores) ----
__global__ __launch_bounds__(BS, 4) void tp_fused_kernel(
    const float* __restrict__ rbf, const float* __restrict__ rsh,
    const int* __restrict__ ei, const float* __restrict__ s_out,
    const float* __restrict__ sphT,
    const unsigned short* __restrict__ W0g, const unsigned short* __restrict__ W1g,
    const unsigned short* __restrict__ W2g, const unsigned short* __restrict__ Wfq,
    float* __restrict__ out0, unsigned short* __restrict__ msgT)
{
  __shared__ __align__(16) unsigned char smem[81280];
  unsigned short* Tb0 = (unsigned short*)smem;
  unsigned short* Tb1 = (unsigned short*)(smem + 24576);
  unsigned short* gateU = (unsigned short*)smem;
  unsigned short* rbfpadU = (unsigned short*)(smem + 24576);
  unsigned short* X1u = (unsigned short*)(smem + 49152);
  float* RshF = (float*)(smem + 79872);
  int* EdstS = (int*)(smem + 81024);
  int* EsrcS = (int*)(smem + 81152);

  const int tid = threadIdx.x;
  const int wid = tid >> 6, lane = tid & 63;
  const int r = lane & 15, kl = lane >> 4;

  auto MFMA = [](v8bf a, v8bf b, f32x4 c) {
    return __builtin_amdgcn_mfma_f32_16x16x32_bf16(a, b, c, 0, 0, 0);
  };
  auto ldw = [&](const unsigned short* base, int fid) {
    return __builtin_bit_cast(v8bf, *(const us8v*)&base[fid * 512 + lane * 8]);
  };

  auto mfma_l0 = [&](const unsigned short* T, long ebase) {
    f32x4 acc0 = {0.f, 0.f, 0.f, 0.f}, acc1 = {0.f, 0.f, 0.f, 0.f};
    #pragma unroll
    for (int kk = 0; kk < 7; ++kk) {
      v8bf b = ldw(W0g, kk * 8 + wid);
      us8v a0 = *(const us8v*)&T[TSW(r, r * 384 + kl * 8 + kk * 32)];
      us8v a1 = *(const us8v*)&T[TSW(r, (16 + r) * 384 + kl * 8 + kk * 32)];
      acc0 = MFMA(__builtin_bit_cast(v8bf, a0), b, acc0);
      acc1 = MFMA(__builtin_bit_cast(v8bf, a1), b, acc1);
    }
    int col = wid * 16 + r;
    #pragma unroll
    for (int j = 0; j < 4; ++j) {
      msgT[(ebase + kl * 4 + j) * SD + col] = f2bfc(acc0[j]);
      msgT[(ebase + 16 + kl * 4 + j) * SD + col] = f2bfc(acc1[j]);
    }
  };

  auto mfma_l1 = [&](const unsigned short* T, int k, long ebase) {
    const int mt = wid >> 2, nt = wid & 3;
    f32x4 acc = {0.f, 0.f, 0.f, 0.f};
    #pragma unroll
    for (int kk = 0; kk < 12; ++kk) {
      v8bf b = ldw(W1g, kk * 4 + nt);
      us8v a = *(const us8v*)&T[TSW(r, (mt * 16 + r) * 384 + kl * 8 + kk * 32)];
      acc = MFMA(__builtin_bit_cast(v8bf, a), b, acc);
    }
    int col = 128 + k * 64 + nt * 16 + r;
    #pragma unroll
    for (int j = 0; j < 4; ++j)
      msgT[(ebase + mt * 16 + kl * 4 + j) * SD + col] = f2bfc(acc[j]);
  };

  // l2: ONE wave owns each (edge-quadrant, col-half): all 11 k-frags in-wave
  // (the R4 kh-split relied on atomics to combine partials; stores need a
  // single owner per output element).
  auto mfma_l2 = [&](const unsigned short* T, int K, long ebase) {
    if (wid < 4) {
      const int mt = (wid >> 1) & 1, ntc = wid & 1;
      f32x4 acc = {0.f, 0.f, 0.f, 0.f};
      #pragma unroll
      for (int kk = 0; kk < 11; ++kk) {
        v8bf b = ldw(W2g, (kk % 6) * 4 + (kk / 6) * 2 + ntc);
        us8v a = *(const us8v*)&T[TSW(r, (mt * 16 + r) * 384 + kk * 32 + kl * 8)];
        acc = MFMA(__builtin_bit_cast(v8bf, a), b, acc);
      }
      int col = 320 + K * 32 + ntc * 16 + r;
      #pragma unroll
      for (int j = 0; j < 4; ++j)
        msgT[(ebase + mt * 16 + kl * 4 + j) * SD + col] = f2bfc(acc[j]);
    }
  };

  for (int tile = blockIdx.x; tile < NE / 32; tile += gridDim.x) {
    const int e0 = tile * 32;
    const long ebase = e0;
    // ---- stage (original edge order: coalesced) ----
    for (int i = tid; i < 32; i += BS) { EdstS[i] = ei[e0 + i]; EsrcS[i] = ei[NE + e0 + i]; }
    for (int i = tid; i < 288; i += BS) RshF[i] = rsh[(long)e0 * 9 + i];
    for (int i = tid; i < 1024; i += BS) {
      int e = i >> 5, b = i & 31;
      rbfpadU[e * 40 + b] = (b < 20) ? f2bfc(rbf[(long)(e0 + e) * NB + b]) : (unsigned short)0;
    }
    __syncthreads();
    // ---- filt MFMA -> gate (bf16 LDS) + scalar msg (atomics, unchanged) ----
    {
      us8v ra0 = *(const us8v*)&rbfpadU[r * 40 + kl * 8];
      us8v ra1 = *(const us8v*)&rbfpadU[(16 + r) * 40 + kl * 8];
      v8bf av0 = __builtin_bit_cast(v8bf, ra0);
      v8bf av1 = __builtin_bit_cast(v8bf, ra1);
      #pragma unroll
      for (int q = 0; q < 6; ++q) {
        int t44 = wid + q * 8;
        if (t44 < 44) {
          int mt = t44 & 1, nt = t44 >> 1;
          v8bf b = ldw(Wfq, q * 8 + wid);
          f32x4 acc = {0.f, 0.f, 0.f, 0.f};
          acc = MFMA(mt ? av1 : av0, b, acc);
          int gi = nt * 16 + r;
          #pragma unroll
          for (int j = 0; j < 4; ++j) {
            int e = mt * 16 + kl * 4 + j;
            float so = s_out[(long)EsrcS[e] * NH + gi];
            float val = acc[j] * so;
            if (nt < 14) gateU[e * 232 + gi] = f2bfc(val);
            else unsafeAtomicAdd(&out0[(long)EdstS[e] * ND + (gi - 224)], val);
          }
        }
      }
    }
    __syncthreads();
    // ---- X1 build (all-vector loads from component-major sphT) ----
    for (int it = tid; it < 1920; it += BS) {
      int e = it / 60, cb = it - e * 60, c0 = cb * 8;
      long srow = (long)EsrcS[e] * SD;
      int gidx = (c0 < 128) ? c0 : (c0 < 320) ? 128 + (c0 & 63) : 192 + (c0 & 31);
      us8v gv = *(const us8v*)&gateU[e * 232 + gidx];
      const float4 sa = *(const float4*)&sphT[srow + c0];
      const float4 sb = *(const float4*)&sphT[srow + c0 + 4];
      float sv[8] = {sa.x, sa.y, sa.z, sa.w, sb.x, sb.y, sb.z, sb.w};
      v8bf o;
      #pragma unroll
      for (int i = 0; i < 8; ++i) o[i] = (__bf16)(sv[i] * bf2f(gv[i]));
      *(us8v*)&X1u[e * 480 + c0] = __builtin_bit_cast(us8v, o);
    }
    __syncthreads();
    // ---- 9 phases, double-buffered T, dense stores ----
    build0(Tb0, X1u, RshF, tid); __syncthreads();
    build1<0>(Tb1, X1u, RshF, tid); mfma_l0(Tb0, ebase); __syncthreads();
    build1<1>(Tb0, X1u, RshF, tid); mfma_l1(Tb1, 0, ebase); __syncthreads();
    build1<2>(Tb1, X1u, RshF, tid); mfma_l1(Tb0, 1, ebase); __syncthreads();
    build2<0>(Tb0, X1u, RshF, tid); mfma_l1(Tb1, 2, ebase); __syncthreads();
    build2<1>(Tb1, X1u, RshF, tid); mfma_l2(Tb0, 0, ebase); __syncthreads();
    build2<2>(Tb0, X1u, RshF, tid); mfma_l2(Tb1, 1, ebase); __syncthreads();
    build2<3>(Tb1, X1u, RshF, tid); mfma_l2(Tb0, 2, ebase); __syncthreads();
    build2<4>(Tb0, X1u, RshF, tid); mfma_l2(Tb1, 3, ebase); __syncthreads();
    mfma_l2(Tb0, 4, ebase); __syncthreads();
  }
}

// ---------------- Gather: out1[n] = sphT[n] + sum_{e in CSR(n)} msgT[e] ----
__global__ __launch_bounds__(512) void gather_kernel(
    const float* __restrict__ sphT, const unsigned short* __restrict__ msgT,
    const int* __restrict__ cnt, const int* __restrict__ cursor,
    const int* __restrict__ es_eid, float* __restrict__ out1)
{
  __shared__ int eids[128];
  __shared__ int s_start, s_deg;
  const int n = blockIdx.x, t = threadIdx.x;
  if (t == 0) {
    int end = cursor[n], d = cnt[n];
    s_start = end - d;
    s_deg = (d > 128) ? 128 : d;
  }
  __syncthreads();
  for (int i = t; i < s_deg; i += 512) eids[i] = es_eid[s_start + i];
  __syncthreads();
  if (t < SD) {
    int tT = t2tT(t);
    float sum = sphT[(long)n * SD + tT];
    for (int i = 0; i < s_deg; ++i)
      sum += bf2f(msgT[(long)eids[i] * SD + tT]);
    out1[(long)n * SD + t] = sum;
  }
}

extern "C" void kernel_launch(void* const* d_in, const int* in_sizes, int n_in,
                              void* d_out, int out_size, void* d_ws, size_t ws_size,
                              hipStream_t stream)
{
  const float* xs   = (const float*)d_in[0];
  const float* xsph = (const float*)d_in[1];
  const float* rbf  = (const float*)d_in[2];
  const float* rsh  = (const float*)d_in[3];
  const int*   ei   = (const int*)d_in[4];
  const float* lnw  = (const float*)d_in[5];
  const float* lnb  = (const float*)d_in[6];
  const float* o3w  = (const float*)d_in[7];
  const float* o3b  = (const float*)d_in[8];
  const float* w1   = (const float*)d_in[9];
  const float* b1   = (const float*)d_in[10];
  const float* w2   = (const float*)d_in[11];
  const float* b2   = (const float*)d_in[12];
  const float* rbfw = (const float*)d_in[13];
  const float* tpw  = (const float*)d_in[14];

  float* out0 = (float*)d_out;
  float* out1 = out0 + (size_t)NN * ND;

  float* ws      = (float*)d_ws;
  float* s_in    = ws;                              // 1,280,000 f
  float* sphT    = ws + (size_t)NN * ND;            // 4,800,000 f (component-major)
  float* s_out   = ws + (size_t)NN * (ND + SD);     // 3,520,000 f
  unsigned short* msgT = (unsigned short*)(ws + (size_t)NN * (ND + SD + NH)); // 48M ush = 96MB
  unsigned short* wbase = msgT + (size_t)NE * SD;
  unsigned short* W0g = wbase;              // 28672
  unsigned short* W1g = wbase + 28672;      // 24576
  unsigned short* W2g = wbase + 53248;      // 12288
  unsigned short* Wfq = wbase + 65536;      // 24576  (total 90112 ush)
  int* ibase  = (int*)(wbase + 90112);
  int* cnt    = ibase;               // 10000
  int* cursor = ibase + 10000;       // 10000
  int* es_eid = ibase + 20000;       // 100000

  hipMemsetAsync(cnt, 0, (size_t)NN * sizeof(int), stream);
  sort_hist<<<(NE + 255) / 256, 256, 0, stream>>>(ei, cnt);
  sort_scan<<<1, 1024, 0, stream>>>(cnt, cursor);
  sort_scatter<<<(NE + 255) / 256, 256, 0, stream>>>(ei, cursor, es_eid);
  prep_w_kernel<<<352, 256, 0, stream>>>(tpw, rbfw, W0g, W1g, W2g, Wfq);
  node_ln_kernel<<<NN, 128, 0, stream>>>(xs, xsph, lnw, lnb, o3w, o3b, s_in, sphT, out0);
  mlp_kernel<<<NN / NPB, 256, 0, stream>>>(s_in, w1, b1, w2, b2, s_out);
  tp_fused_kernel<<<512, BS, 0, stream>>>(rbf, rsh, ei, s_out, sphT,
                                          W0g, W1g, W2g, Wfq, out0, msgT);
  gather_kernel<<<NN, 512, 0, stream>>>(sphT, msgT, cnt, cursor, es_eid, out1);
}

// Round 9
// 658.741 us; speedup vs baseline: 1.6495x; 1.0614x over previous
//
#include <hip/hip_runtime.h>

#define NN 10000
#define NE 100000
#define ND 128
#define NB 20
#define NIR 224
#define NH 352
#define SD 480
#define BS 512
#define ET 16
#define NTILES (NE / ET)

// CG / normalization constants (verified in R1/R2)
#define CR   0.70710678118654752f
#define CA   0.40824829046386302f
#define HA   0.20412414523193151f
#define HR   0.35355339059327376f
#define C110 0.57735026918962576f
#define C220 0.44721359549995794f
#define C111 0.40824829046386302f
#define C11X 0.44721359549995794f
#define C221 0.36514837167011074f
#define C222 0.58554004376912270f
#define S32  0.86602540378443865f
#define PW0  0.066815310478106094f
#define PW1  0.088388347648318447f
#define PW2  0.11918321088232916f

typedef __bf16 v8bf __attribute__((ext_vector_type(8)));
typedef unsigned short us8v __attribute__((ext_vector_type(8)));
typedef float f32x4 __attribute__((ext_vector_type(4)));

__device__ __forceinline__ unsigned short f2bfc(float f) {
  __bf16 h = (__bf16)f;
  return __builtin_bit_cast(unsigned short, h);
}
__device__ __forceinline__ float bf2f(unsigned short h) {
  unsigned int u = ((unsigned int)h) << 16;
  return __builtin_bit_cast(float, u);
}

__device__ __forceinline__ float warpReduceSum(float v) {
  #pragma unroll
  for (int off = 32; off > 0; off >>= 1) v += __shfl_down(v, off, 64);
  return v;
}

__device__ __forceinline__ int t2tT(int t) {
  if (t < 128) return t;
  if (t < 320) { int c = t - 128; return 128 + (c % 3) * 64 + c / 3; }
  int c = t - 320; return 320 + (c % 5) * 32 + c / 5;
}

// ---------------- Sort kernels (CSR for gather only) -------------------------
__global__ __launch_bounds__(256) void sort_hist(const int* __restrict__ ei, int* __restrict__ cnt) {
  int e = blockIdx.x * 256 + threadIdx.x;
  if (e < NE) atomicAdd(&cnt[ei[e]], 1);
}

__global__ __launch_bounds__(1024) void sort_scan(const int* __restrict__ cnt, int* __restrict__ cursor) {
  __shared__ int part[1024];
  const int t = threadIdx.x;
  int loc[10]; int s = 0;
  #pragma unroll
  for (int j = 0; j < 10; ++j) { int idx = t * 10 + j; int v = (idx < NN) ? cnt[idx] : 0; loc[j] = s; s += v; }
  part[t] = s; __syncthreads();
  for (int d = 1; d < 1024; d <<= 1) {
    int v = (t >= d) ? part[t - d] : 0; __syncthreads();
    part[t] += v; __syncthreads();
  }
  int off = part[t] - s;
  #pragma unroll
  for (int j = 0; j < 10; ++j) { int idx = t * 10 + j; if (idx < NN) cursor[idx] = off + loc[j]; }
}

__global__ __launch_bounds__(256) void sort_scatter(
    const int* __restrict__ ei, int* __restrict__ cursor, int* __restrict__ es_eid) {
  int e = blockIdx.x * 256 + threadIdx.x;
  if (e < NE) {
    int d = ei[e];
    int pos = atomicAdd(&cursor[d], 1);
    es_eid[pos] = e;
  }
}

// ---------------- Kernel 1: scalar LN + O3 LN (sphT component-major) ---------
__global__ __launch_bounds__(128) void node_ln_kernel(
    const float* __restrict__ xs, const float* __restrict__ xsph,
    const float* __restrict__ lnw, const float* __restrict__ lnb,
    const float* __restrict__ o3w, const float* __restrict__ o3b,
    float* __restrict__ s_in, float* __restrict__ sphT,
    float* __restrict__ out0)
{
  const int n = blockIdx.x, t = threadIdx.x;
  __shared__ float red[4];

  auto reduce2 = [&](float a, float b) {
    a = warpReduceSum(a); b = warpReduceSum(b);
    if ((t & 63) == 0) { red[(t >> 6) * 2] = a; red[(t >> 6) * 2 + 1] = b; }
    __syncthreads();
    float ra = red[0] + red[2], rb = red[1] + red[3];
    __syncthreads();
    return make_float2(ra, rb);
  };

  float x = xs[n * ND + t];
  float2 sr = reduce2(x, x * x);
  float mu = sr.x * (1.f / ND);
  float var = sr.y * (1.f / ND) - mu * mu;
  float y = (x - mu) * rsqrtf(var + 1e-5f) * lnw[t] + lnb[t];
  s_in[n * ND + t] = y; out0[n * ND + t] = y;

  float f = xsph[n * SD + t];
  float2 r0 = reduce2(f, f * f);
  float m0 = r0.x * (1.f / 128.f);
  float nrm0 = r0.y * (1.f / 128.f) - m0 * m0;
  float y0 = (f - m0) * rsqrtf(nrm0 + 1e-5f) * o3w[t] + o3b[t];
  sphT[n * SD + t] = y0;

  float f1a = xsph[n * SD + 128 + t];
  float f1b = (t < 64) ? xsph[n * SD + 256 + t] : 0.f;
  float2 r1 = reduce2(f1a * f1a + f1b * f1b, 0.f);
  float rs1 = rsqrtf(r1.x * (1.f / 192.f) + 1e-5f);
  sphT[n * SD + t2tT(128 + t)] = f1a * rs1 * o3w[128 + t / 3];
  if (t < 64)
    sphT[n * SD + t2tT(256 + t)] = f1b * rs1 * o3w[128 + (128 + t) / 3];

  float f2a = xsph[n * SD + 320 + t];
  float f2b = (t < 32) ? xsph[n * SD + 448 + t] : 0.f;
  float2 r2 = reduce2(f2a * f2a + f2b * f2b, 0.f);
  float rs2 = rsqrtf(r2.x * (1.f / 160.f) + 1e-5f);
  sphT[n * SD + t2tT(320 + t)] = f2a * rs2 * o3w[192 + t / 5];
  if (t < 32)
    sphT[n * SD + t2tT(448 + t)] = f2b * rs2 * o3w[192 + (128 + t) / 5];
}

// ---------------- Kernel 2: node MLP (unchanged, verified) -------------------
#define NPB 8
__global__ __launch_bounds__(256) void mlp_kernel(
    const float* __restrict__ s_in, const float* __restrict__ w1,
    const float* __restrict__ b1, const float* __restrict__ w2,
    const float* __restrict__ b2, float* __restrict__ s_out)
{
  __shared__ float sIn[NPB][ND];
  __shared__ float sH[NPB][ND];
  const int t = threadIdx.x;
  const int n0 = blockIdx.x * NPB;
  for (int i = t; i < NPB * ND; i += 256) sIn[i >> 7][i & 127] = s_in[n0 * ND + i];
  __syncthreads();
  {
    const int j = t & 127, g = t >> 7;
    float acc[4] = {0.f, 0.f, 0.f, 0.f};
    for (int k = 0; k < ND; ++k) {
      float w = w1[k * ND + j];
      #pragma unroll
      for (int i = 0; i < 4; ++i) acc[i] = fmaf(sIn[g + 2 * i][k], w, acc[i]);
    }
    #pragma unroll
    for (int i = 0; i < 4; ++i) {
      float z = acc[i] + b1[j];
      sH[g + 2 * i][j] = z / (1.f + __expf(-z));
    }
  }
  __syncthreads();
  for (int jb = 0; jb < 2; ++jb) {
    int j = jb * 256 + t;
    if (j < NH) {
      float acc[NPB];
      #pragma unroll
      for (int i = 0; i < NPB; ++i) acc[i] = b2[j];
      for (int k = 0; k < ND; ++k) {
        float w = w2[k * NH + j];
        #pragma unroll
        for (int i = 0; i < NPB; ++i) acc[i] = fmaf(sH[i][k], w, acc[i]);
      }
      #pragma unroll
      for (int i = 0; i < NPB; ++i) s_out[(n0 + i) * NH + j] = acc[i];
    }
  }
}

// ---------------- W element fetchers (verified offsets) ----------------------
__device__ __forceinline__ float wc0(const float* w, int u, int j) {
  int off = (u < 128) ? u * 128 : (u < 192) ? 16384 + (u - 128) * 128 : 24576 + (u - 192) * 128;
  return w[off + j];
}
__device__ __forceinline__ float wc1(const float* w, int u, int j) {
  int off = (u < 128) ? 28672 + u * 64 : (u < 192) ? 36864 + (u - 128) * 64
          : (u < 256) ? 40960 + (u - 192) * 64 : (u < 320) ? 45056 + (u - 256) * 64
          : (u < 352) ? 49152 + (u - 320) * 64 : 51200 + (u - 352) * 64;
  return w[off + j];
}
__device__ __forceinline__ float wc2(const float* w, int u, int j) {
  int off = (u < 128) ? 53248 + u * 32 : (u < 192) ? 57344 + (u - 128) * 32
          : (u < 256) ? 59392 + (u - 192) * 32 : (u < 288) ? 61440 + (u - 256) * 32
          : (u < 320) ? 62464 + (u - 288) * 32 : 63488 + (u - 320) * 32;
  return w[off + j];
}

// ---------------- Prep kernel: W -> bf16 fragment layout ---------------------
// W0g: 7*8*512, W1g: 12*4*512, W2g: 6*2*2*512, Wfq: 3*8*512 (t22 = wid+q*8)
__global__ __launch_bounds__(256) void prep_w_kernel(
    const float* __restrict__ tpw, const float* __restrict__ rbf_w,
    unsigned short* __restrict__ W0g, unsigned short* __restrict__ W1g,
    unsigned short* __restrict__ W2g, unsigned short* __restrict__ Wfq)
{
  int gid = blockIdx.x * 256 + threadIdx.x;
  int i = gid & 7, lane = (gid >> 3) & 63;
  int r = lane & 15, kl = lane >> 4;
  if (gid < 28672) {
    int fid = gid >> 9, kk = fid >> 3, wid = fid & 7;
    W0g[gid] = f2bfc(wc0(tpw, kk * 32 + kl * 8 + i, wid * 16 + r));
  } else if (gid < 53248) {
    int g = gid - 28672, fid = g >> 9, kk = fid >> 2, nt = fid & 3;
    W1g[g] = f2bfc(wc1(tpw, kk * 32 + kl * 8 + i, nt * 16 + r));
  } else if (gid < 65536) {
    int g = gid - 53248, fid = g >> 9, q = fid >> 2, kh = (fid >> 1) & 1, ntc = fid & 1;
    int kk = kh * 6 + q;
    W2g[g] = (kk < 11) ? f2bfc(wc2(tpw, kk * 32 + kl * 8 + i, ntc * 16 + r)) : (unsigned short)0;
  } else if (gid < 77824) {
    int g = gid - 65536, fid = g >> 9, q = fid >> 3, wid = fid & 7;
    int t22 = wid + q * 8, k = kl * 8 + i;
    Wfq[g] = (t22 < 22 && k < 20) ? f2bfc(rbf_w[k * NH + t22 * 16 + r]) : (unsigned short)0;
  }
}

// T-element emitter
template<int M>
__device__ __forceinline__ void emit_dot(unsigned short* dst, const unsigned short* x1,
                                         const int* offs, const float* cf) {
  us8v xv[M];
  #pragma unroll
  for (int m = 0; m < M; ++m) xv[m] = *(const us8v*)&x1[offs[m]];
  v8bf o;
  #pragma unroll
  for (int i = 0; i < 8; ++i) {
    float a = 0.f;
    #pragma unroll
    for (int m = 0; m < M; ++m) a = fmaf(cf[m], bf2f(xv[m][i]), a);
    o[i] = (__bf16)a;
  }
  *(us8v*)dst = __builtin_bit_cast(us8v, o);
}

// ---------------- T-slice builders (ET=16) -----------------------------------
#define TSW(e, idx) ((idx) ^ (((e) & 7) << 3))

__device__ __forceinline__ void build0(unsigned short* Tb, const unsigned short* X1u,
                                       const float* RshF, int tid) {
  for (int it = tid; it < ET * 28; it += BS) {
    int e = it / 28, ub = it - e * 28, u0 = ub * 8;
    const float* R = &RshF[e * 9];
    const unsigned short* x1 = &X1u[e * 480];
    unsigned short* dst = Tb + TSW(e, e * 384 + u0);
    if (u0 < 128) {
      float cf[1] = { PW0 * R[0] };
      int offs[1] = { u0 };
      emit_dot<1>(dst, x1, offs, cf);
    } else if (u0 < 192) {
      int m0 = u0 - 128;
      float cf[3] = { PW0 * C110 * R[1], PW0 * C110 * R[2], PW0 * C110 * R[3] };
      int offs[3] = { 128 + m0, 192 + m0, 256 + m0 };
      emit_dot<3>(dst, x1, offs, cf);
    } else {
      int m0 = u0 - 192;
      float cf[5] = { PW0 * C220 * R[4], PW0 * C220 * R[5], PW0 * C220 * R[6],
                      PW0 * C220 * R[7], PW0 * C220 * R[8] };
      int offs[5] = { 320 + m0, 352 + m0, 384 + m0, 416 + m0, 448 + m0 };
      emit_dot<5>(dst, x1, offs, cf);
    }
  }
}

template<int k>
__device__ __forceinline__ void build1(unsigned short* Tb, const unsigned short* X1u,
                                       const float* RshF, int tid) {
  for (int it = tid; it < ET * 48; it += BS) {
    int e = it / 48, ub = it - e * 48, u0 = ub * 8;
    const float* R = &RshF[e * 9];
    const unsigned short* x1 = &X1u[e * 480];
    unsigned short* dst = Tb + TSW(e, e * 384 + u0);
    const float s = R[0], v0 = R[1], v1 = R[2], v2 = R[3];
    const float w0 = R[4], w1 = R[5], w2 = R[6], w3 = R[7], w4 = R[8];
    if (u0 < 128) {
      float cf[1] = { PW1 * C110 * R[1 + k] };
      int offs[1] = { u0 };
      emit_dot<1>(dst, x1, offs, cf);
    } else if (u0 < 192) {
      float cf[1] = { PW1 * C110 * s };
      int offs[1] = { 128 + k * 64 + (u0 - 128) };
      emit_dot<1>(dst, x1, offs, cf);
    } else if (u0 < 256) {
      constexpr int ka = (k + 1) % 3, kb = (k + 2) % 3;
      int m0 = u0 - 192;
      float cf[2] = { PW1 * C111 * R[1 + kb], -PW1 * C111 * R[1 + ka] };
      int offs[2] = { 128 + ka * 64 + m0, 128 + kb * 64 + m0 };
      emit_dot<2>(dst, x1, offs, cf);
    } else if (u0 < 320) {
      int m0 = u0 - 256;
      float cf[3];
      if constexpr (k == 0) { cf[0] = PW1*C11X*(-CA*w2 + CR*w4); cf[1] = PW1*C11X*CR*w0; cf[2] = PW1*C11X*CR*w3; }
      else if constexpr (k == 1) { cf[0] = PW1*C11X*CR*w0; cf[1] = PW1*C11X*(-CA*w2 - CR*w4); cf[2] = PW1*C11X*CR*w1; }
      else { cf[0] = PW1*C11X*CR*w3; cf[1] = PW1*C11X*CR*w1; cf[2] = PW1*C11X*2.f*CA*w2; }
      int offs[3] = { 128 + m0, 192 + m0, 256 + m0 };
      emit_dot<3>(dst, x1, offs, cf);
    } else if (u0 < 352) {
      int m0 = u0 - 320;
      if constexpr (k == 0) {
        float cf[4] = { PW1*C11X*CR*v1, PW1*C11X*(-CA*v0), PW1*C11X*CR*v2, PW1*C11X*CR*v0 };
        int offs[4] = { 320 + m0, 384 + m0, 416 + m0, 448 + m0 };
        emit_dot<4>(dst, x1, offs, cf);
      } else if constexpr (k == 1) {
        float cf[4] = { PW1*C11X*CR*v0, PW1*C11X*CR*v2, PW1*C11X*(-CA*v1), PW1*C11X*(-CR*v1) };
        int offs[4] = { 320 + m0, 352 + m0, 384 + m0, 448 + m0 };
        emit_dot<4>(dst, x1, offs, cf);
      } else {
        float cf[3] = { PW1*C11X*CR*v1, PW1*C11X*2.f*CA*v2, PW1*C11X*CR*v0 };
        int offs[3] = { 352 + m0, 384 + m0, 416 + m0 };
        emit_dot<3>(dst, x1, offs, cf);
      }
    } else {
      int m0 = u0 - 352;
      if constexpr (k == 0) {
        float cf[5] = { PW1*C221*0.5f*w3, PW1*C221*(S32*w2 + 0.5f*w4), PW1*C221*(-S32*w1),
                        PW1*C221*(-0.5f*w0), PW1*C221*(-0.5f*w1) };
        int offs[5] = { 320 + m0, 352 + m0, 384 + m0, 416 + m0, 448 + m0 };
        emit_dot<5>(dst, x1, offs, cf);
      } else if constexpr (k == 1) {
        float cf[5] = { PW1*C221*(-0.5f*w1), PW1*C221*0.5f*w0, PW1*C221*S32*w3,
                        PW1*C221*(-S32*w2 + 0.5f*w4), PW1*C221*(-0.5f*w3) };
        int offs[5] = { 320 + m0, 352 + m0, 384 + m0, 416 + m0, 448 + m0 };
        emit_dot<5>(dst, x1, offs, cf);
      } else {
        float cf[4] = { PW1*C221*(-w4), PW1*C221*(-0.5f*w3), PW1*C221*0.5f*w1, PW1*C221*w0 };
        int offs[4] = { 320 + m0, 352 + m0, 416 + m0, 448 + m0 };
        emit_dot<4>(dst, x1, offs, cf);
      }
    }
  }
}

template<int K>
__device__ __forceinline__ void build2(unsigned short* Tb, const unsigned short* X1u,
                                       const float* RshF, int tid) {
  for (int it = tid; it < ET * 44; it += BS) {
    int e = it / 44, ub = it - e * 44, u0 = ub * 8;
    const float* R = &RshF[e * 9];
    const unsigned short* x1 = &X1u[e * 480];
    unsigned short* dst = Tb + TSW(e, e * 384 + u0);
    const float s = R[0], v0 = R[1], v1 = R[2], v2 = R[3];
    const float w0 = R[4], w1 = R[5], w2 = R[6], w3 = R[7], w4 = R[8];
    if (u0 < 128) {
      float cf[1] = { PW2 * C220 * R[4 + K] };
      int offs[1] = { u0 };
      emit_dot<1>(dst, x1, offs, cf);
    } else if (u0 < 192) {
      int m0 = u0 - 128;
      if constexpr (K == 0) {
        float cf[2] = { PW2*C11X*CR*v1, PW2*C11X*CR*v0 };
        int offs[2] = { 128 + m0, 192 + m0 };
        emit_dot<2>(dst, x1, offs, cf);
      } else if constexpr (K == 1) {
        float cf[2] = { PW2*C11X*CR*v2, PW2*C11X*CR*v1 };
        int offs[2] = { 192 + m0, 256 + m0 };
        emit_dot<2>(dst, x1, offs, cf);
      } else if constexpr (K == 2) {
        float cf[3] = { PW2*C11X*(-CA*v0), PW2*C11X*(-CA*v1), PW2*C11X*2.f*CA*v2 };
        int offs[3] = { 128 + m0, 192 + m0, 256 + m0 };
        emit_dot<3>(dst, x1, offs, cf);
      } else if constexpr (K == 3) {
        float cf[2] = { PW2*C11X*CR*v2, PW2*C11X*CR*v0 };
        int offs[2] = { 128 + m0, 256 + m0 };
        emit_dot<2>(dst, x1, offs, cf);
      } else {
        float cf[2] = { PW2*C11X*CR*v0, PW2*C11X*(-CR*v1) };
        int offs[2] = { 128 + m0, 192 + m0 };
        emit_dot<2>(dst, x1, offs, cf);
      }
    } else if (u0 < 256) {
      int m0 = u0 - 192;
      if constexpr (K == 2) {
        float cf[2] = { PW2*C221*S32*w1, PW2*C221*(-S32*w3) };
        int offs[2] = { 128 + m0, 192 + m0 };
        emit_dot<2>(dst, x1, offs, cf);
      } else {
        float cf[3];
        if constexpr (K == 0) { cf[0]=PW2*C221*(-0.5f*w3); cf[1]=PW2*C221*0.5f*w1; cf[2]=PW2*C221*w4; }
        else if constexpr (K == 1) { cf[0]=PW2*C221*(-S32*w2 - 0.5f*w4); cf[1]=PW2*C221*(-0.5f*w0); cf[2]=PW2*C221*0.5f*w3; }
        else if constexpr (K == 3) { cf[0]=PW2*C221*0.5f*w0; cf[1]=PW2*C221*(S32*w2 - 0.5f*w4); cf[2]=PW2*C221*(-0.5f*w1); }
        else { cf[0]=PW2*C221*0.5f*w1; cf[1]=PW2*C221*0.5f*w3; cf[2]=PW2*C221*(-w0); }
        int offs[3] = { 128 + m0, 192 + m0, 256 + m0 };
        emit_dot<3>(dst, x1, offs, cf);
      }
    } else if (u0 < 288) {
      int m0 = u0 - 256;
      float cf[1] = { PW2 * C220 * s };
      int offs[1] = { 320 + K * 32 + m0 };
      emit_dot<1>(dst, x1, offs, cf);
    } else if (u0 < 320) {
      int m0 = u0 - 288;
      if constexpr (K == 0) {
        float cf[3] = { PW2*C221*0.5f*v1, PW2*C221*(-0.5f*v0), PW2*C221*v2 };
        int offs[3] = { 352 + m0, 416 + m0, 448 + m0 };
        emit_dot<3>(dst, x1, offs, cf);
      } else if constexpr (K == 1) {
        float cf[4] = { PW2*C221*(-0.5f*v1), PW2*C221*(-S32*v0), PW2*C221*0.5f*v2, PW2*C221*(-0.5f*v0) };
        int offs[4] = { 320 + m0, 384 + m0, 416 + m0, 448 + m0 };
        emit_dot<4>(dst, x1, offs, cf);
      } else if constexpr (K == 2) {
        float cf[2] = { PW2*C221*S32*v0, PW2*C221*(-S32*v1) };
        int offs[2] = { 352 + m0, 416 + m0 };
        emit_dot<2>(dst, x1, offs, cf);
      } else if constexpr (K == 3) {
        float cf[4] = { PW2*C221*0.5f*v0, PW2*C221*(-0.5f*v2), PW2*C221*S32*v1, PW2*C221*(-0.5f*v1) };
        int offs[4] = { 320 + m0, 352 + m0, 384 + m0, 448 + m0 };
        emit_dot<4>(dst, x1, offs, cf);
      } else {
        float cf[3] = { PW2*C221*(-v2), PW2*C221*0.5f*v0, PW2*C221*0.5f*v1 };
        int offs[3] = { 320 + m0, 352 + m0, 416 + m0 };
        emit_dot<3>(dst, x1, offs, cf);
      }
    } else {
      int m0 = u0 - 320;
      if constexpr (K == 0) {
        float cf[4] = { PW2*C222*(-CA*w2), PW2*C222*HR*w3, PW2*C222*(-CA*w0), PW2*C222*HR*w1 };
        int offs[4] = { 320 + m0, 352 + m0, 384 + m0, 416 + m0 };
        emit_dot<4>(dst, x1, offs, cf);
      } else if constexpr (K == 4) {
        float cf[4] = { PW2*C222*(-HR*w1), PW2*C222*(-CA*w4), PW2*C222*HR*w3, PW2*C222*(-CA*w2) };
        int offs[4] = { 352 + m0, 384 + m0, 416 + m0, 448 + m0 };
        emit_dot<4>(dst, x1, offs, cf);
      } else {
        float cf[5];
        if constexpr (K == 1) { cf[0]=PW2*C222*HR*w3; cf[1]=PW2*C222*(HA*w2 - HR*w4); cf[2]=PW2*C222*HA*w1; cf[3]=PW2*C222*HR*w0; cf[4]=PW2*C222*(-HR*w1); }
        else if constexpr (K == 2) { cf[0]=PW2*C222*(-CA*w0); cf[1]=PW2*C222*HA*w1; cf[2]=PW2*C222*CA*w2; cf[3]=PW2*C222*HA*w3; cf[4]=PW2*C222*(-CA*w4); }
        else { cf[0]=PW2*C222*HR*w1; cf[1]=PW2*C222*HR*w0; cf[2]=PW2*C222*HA*w3; cf[3]=PW2*C222*(HA*w2 + HR*w4); cf[4]=PW2*C222*HR*w3; }
        int offs[5] = { 320 + m0, 352 + m0, 384 + m0, 416 + m0, 448 + m0 };
        emit_dot<5>(dst, x1, offs, cf);
      }
    }
  }
}

// ---------------- Fused TP kernel (ET=16, ~40KB LDS -> 4 blocks/CU) ----------
// LDS map: Tb0 [0,12288) Tb1 [12288,24576) X1u [24576,39936)
//          RshF [39936,40512) Edst [40512,40576) Esrc [40576,40640)
//          gateU (16x232 ush = 7424) aliases Tb0; rbfpadU (1280) aliases Tb1.
__global__ __launch_bounds__(BS, 8) void tp_fused_kernel(
    const float* __restrict__ rbf, const float* __restrict__ rsh,
    const int* __restrict__ ei, const float* __restrict__ s_out,
    const float* __restrict__ sphT,
    const unsigned short* __restrict__ W0g, const unsigned short* __restrict__ W1g,
    const unsigned short* __restrict__ W2g, const unsigned short* __restrict__ Wfq,
    float* __restrict__ out0, unsigned short* __restrict__ msgT)
{
  __shared__ __align__(16) unsigned char smem[40640];
  unsigned short* Tb0 = (unsigned short*)smem;
  unsigned short* Tb1 = (unsigned short*)(smem + 12288);
  unsigned short* gateU = (unsigned short*)smem;
  unsigned short* rbfpadU = (unsigned short*)(smem + 12288);
  unsigned short* X1u = (unsigned short*)(smem + 24576);
  float* RshF = (float*)(smem + 39936);
  int* EdstS = (int*)(smem + 40512);
  int* EsrcS = (int*)(smem + 40576);

  const int tid = threadIdx.x;
  const int wid = tid >> 6, lane = tid & 63;
  const int r = lane & 15, kl = lane >> 4;

  auto MFMA = [](v8bf a, v8bf b, f32x4 c) {
    return __builtin_amdgcn_mfma_f32_16x16x32_bf16(a, b, c, 0, 0, 0);
  };
  auto ldw = [&](const unsigned short* base, int fid) {
    return __builtin_bit_cast(v8bf, *(const us8v*)&base[fid * 512 + lane * 8]);
  };

  auto mfma_l0 = [&](const unsigned short* T, long ebase) {
    f32x4 acc = {0.f, 0.f, 0.f, 0.f};
    #pragma unroll
    for (int kk = 0; kk < 7; ++kk) {
      v8bf b = ldw(W0g, kk * 8 + wid);
      us8v a = *(const us8v*)&T[TSW(r, r * 384 + kl * 8 + kk * 32)];
      acc = MFMA(__builtin_bit_cast(v8bf, a), b, acc);
    }
    int col = wid * 16 + r;
    #pragma unroll
    for (int j = 0; j < 4; ++j)
      msgT[(ebase + kl * 4 + j) * SD + col] = f2bfc(acc[j]);
  };

  auto mfma_l1 = [&](const unsigned short* T, int k, long ebase) {
    if (wid < 4) {
      const int nt = wid;
      f32x4 acc = {0.f, 0.f, 0.f, 0.f};
      #pragma unroll
      for (int kk = 0; kk < 12; ++kk) {
        v8bf b = ldw(W1g, kk * 4 + nt);
        us8v a = *(const us8v*)&T[TSW(r, r * 384 + kl * 8 + kk * 32)];
        acc = MFMA(__builtin_bit_cast(v8bf, a), b, acc);
      }
      int col = 128 + k * 64 + nt * 16 + r;
      #pragma unroll
      for (int j = 0; j < 4; ++j)
        msgT[(ebase + kl * 4 + j) * SD + col] = f2bfc(acc[j]);
    }
  };

  auto mfma_l2 = [&](const unsigned short* T, int K, long ebase) {
    if (wid < 2) {
      const int ntc = wid;
      f32x4 acc = {0.f, 0.f, 0.f, 0.f};
      #pragma unroll
      for (int kk = 0; kk < 11; ++kk) {
        v8bf b = ldw(W2g, (kk % 6) * 4 + (kk / 6) * 2 + ntc);
        us8v a = *(const us8v*)&T[TSW(r, r * 384 + kk * 32 + kl * 8)];
        acc = MFMA(__builtin_bit_cast(v8bf, a), b, acc);
      }
      int col = 320 + K * 32 + ntc * 16 + r;
      #pragma unroll
      for (int j = 0; j < 4; ++j)
        msgT[(ebase + kl * 4 + j) * SD + col] = f2bfc(acc[j]);
    }
  };

  for (int tile = blockIdx.x; tile < NTILES; tile += gridDim.x) {
    const int e0 = tile * ET;
    const long ebase = e0;
    // ---- stage ----
    for (int i = tid; i < ET; i += BS) { EdstS[i] = ei[e0 + i]; EsrcS[i] = ei[NE + e0 + i]; }
    for (int i = tid; i < ET * 9; i += BS) RshF[i] = rsh[(long)e0 * 9 + i];
    for (int i = tid; i < ET * 32; i += BS) {
      int e = i >> 5, b = i & 31;
      rbfpadU[e * 40 + b] = (b < 20) ? f2bfc(rbf[(long)(e0 + e) * NB + b]) : (unsigned short)0;
    }
    __syncthreads();
    // ---- filt MFMA -> gate (bf16 LDS) + scalar msg (atomics) ----
    {
      us8v ra = *(const us8v*)&rbfpadU[r * 40 + kl * 8];
      v8bf av = __builtin_bit_cast(v8bf, ra);
      #pragma unroll
      for (int q = 0; q < 3; ++q) {
        int t22 = wid + q * 8;
        if (t22 < 22) {
          v8bf b = ldw(Wfq, q * 8 + wid);
          f32x4 acc = {0.f, 0.f, 0.f, 0.f};
          acc = MFMA(av, b, acc);
          int gi = t22 * 16 + r;
          #pragma unroll
          for (int j = 0; j < 4; ++j) {
            int e = kl * 4 + j;
            float so = s_out[(long)EsrcS[e] * NH + gi];
            float val = acc[j] * so;
            if (t22 < 14) gateU[e * 232 + gi] = f2bfc(val);
            else unsafeAtomicAdd(&out0[(long)EdstS[e] * ND + (gi - 224)], val);
          }
        }
      }
    }
    __syncthreads();
    // ---- X1 build (vector loads from component-major sphT) ----
    for (int it = tid; it < ET * 60; it += BS) {
      int e = it / 60, cb = it - e * 60, c0 = cb * 8;
      long srow = (long)EsrcS[e] * SD;
      int gidx = (c0 < 128) ? c0 : (c0 < 320) ? 128 + (c0 & 63) : 192 + (c0 & 31);
      us8v gv = *(const us8v*)&gateU[e * 232 + gidx];
      const float4 sa = *(const float4*)&sphT[srow + c0];
      const float4 sb = *(const float4*)&sphT[srow + c0 + 4];
      float sv[8] = {sa.x, sa.y, sa.z, sa.w, sb.x, sb.y, sb.z, sb.w};
      v8bf o;
      #pragma unroll
      for (int i = 0; i < 8; ++i) o[i] = (__bf16)(sv[i] * bf2f(gv[i]));
      *(us8v*)&X1u[e * 480 + c0] = __builtin_bit_cast(us8v, o);
    }
    __syncthreads();
    // ---- 9 phases, double-buffered T, dense stores ----
    build0(Tb0, X1u, RshF, tid); __syncthreads();
    build1<0>(Tb1, X1u, RshF, tid); mfma_l0(Tb0, ebase); __syncthreads();
    build1<1>(Tb0, X1u, RshF, tid); mfma_l1(Tb1, 0, ebase); __syncthreads();
    build1<2>(Tb1, X1u, RshF, tid); mfma_l1(Tb0, 1, ebase); __syncthreads();
    build2<0>(Tb0, X1u, RshF, tid); mfma_l1(Tb1, 2, ebase); __syncthreads();
    build2<1>(Tb1, X1u, RshF, tid); mfma_l2(Tb0, 0, ebase); __syncthreads();
    build2<2>(Tb0, X1u, RshF, tid); mfma_l2(Tb1, 1, ebase); __syncthreads();
    build2<3>(Tb1, X1u, RshF, tid); mfma_l2(Tb0, 2, ebase); __syncthreads();
    build2<4>(Tb0, X1u, RshF, tid); mfma_l2(Tb1, 3, ebase); __syncthreads();
    mfma_l2(Tb0, 4, ebase); __syncthreads();
  }
}

// ---------------- Gather (coalesced): sum component-major cols, un-permute ---
__global__ __launch_bounds__(512) void gather_kernel(
    const float* __restrict__ sphT, const unsigned short* __restrict__ msgT,
    const int* __restrict__ cnt, const int* __restrict__ cursor,
    const int* __restrict__ es_eid, float* __restrict__ out1)
{
  __shared__ float sumT[SD];
  __shared__ int eids[160];
  __shared__ int s_deg;
  const int n = blockIdx.x, t = threadIdx.x;
  if (t == 0) {
    int d = cnt[n];
    s_deg = (d > 160) ? 160 : d;
  }
  __syncthreads();
  int deg = s_deg;
  int start = cursor[n] - cnt[n];
  for (int i = t; i < deg; i += 512) eids[i] = es_eid[start + i];
  __syncthreads();
  if (t < SD) {
    float acc = 0.f;
    for (int i = 0; i < deg; ++i)
      acc += bf2f(msgT[(long)eids[i] * SD + t]);   // coalesced: adjacent t
    sumT[t] = acc;
  }
  __syncthreads();
  if (t < SD) {
    int tT = t2tT(t);
    out1[(long)n * SD + t] = sphT[(long)n * SD + tT] + sumT[tT];
  }
}

extern "C" void kernel_launch(void* const* d_in, const int* in_sizes, int n_in,
                              void* d_out, int out_size, void* d_ws, size_t ws_size,
                              hipStream_t stream)
{
  const float* xs   = (const float*)d_in[0];
  const float* xsph = (const float*)d_in[1];
  const float* rbf  = (const float*)d_in[2];
  const float* rsh  = (const float*)d_in[3];
  const int*   ei   = (const int*)d_in[4];
  const float* lnw  = (const float*)d_in[5];
  const float* lnb  = (const float*)d_in[6];
  const float* o3w  = (const float*)d_in[7];
  const float* o3b  = (const float*)d_in[8];
  const float* w1   = (const float*)d_in[9];
  const float* b1   = (const float*)d_in[10];
  const float* w2   = (const float*)d_in[11];
  const float* b2   = (const float*)d_in[12];
  const float* rbfw = (const float*)d_in[13];
  const float* tpw  = (const float*)d_in[14];

  float* out0 = (float*)d_out;
  float* out1 = out0 + (size_t)NN * ND;

  float* ws      = (float*)d_ws;
  float* s_in    = ws;
  float* sphT    = ws + (size_t)NN * ND;
  float* s_out   = ws + (size_t)NN * (ND + SD);
  unsigned short* msgT = (unsigned short*)(ws + (size_t)NN * (ND + SD + NH));
  unsigned short* wbase = msgT + (size_t)NE * SD;
  unsigned short* W0g = wbase;              // 28672
  unsigned short* W1g = wbase + 28672;      // 24576
  unsigned short* W2g = wbase + 53248;      // 12288
  unsigned short* Wfq = wbase + 65536;      // 12288 (24 fids)
  int* ibase  = (int*)(wbase + 77824);
  int* cnt    = ibase;               // 10000
  int* cursor = ibase + 10000;       // 10000
  int* es_eid = ibase + 20000;       // 100000

  hipMemsetAsync(cnt, 0, (size_t)NN * sizeof(int), stream);
  sort_hist<<<(NE + 255) / 256, 256, 0, stream>>>(ei, cnt);
  sort_scan<<<1, 1024, 0, stream>>>(cnt, cursor);
  sort_scatter<<<(NE + 255) / 256, 256, 0, stream>>>(ei, cursor, es_eid);
  prep_w_kernel<<<304, 256, 0, stream>>>(tpw, rbfw, W0g, W1g, W2g, Wfq);
  node_ln_kernel<<<NN, 128, 0, stream>>>(xs, xsph, lnw, lnb, o3w, o3b, s_in, sphT, out0);
  mlp_kernel<<<NN / NPB, 256, 0, stream>>>(s_in, w1, b1, w2, b2, s_out);
  tp_fused_kernel<<<1024, BS, 0, stream>>>(rbf, rsh, ei, s_out, sphT,
                                           W0g, W1g, W2g, Wfq, out0, msgT);
  gather_kernel<<<NN, 512, 0, stream>>>(sphT, msgT, cnt, cursor, es_eid, out1);
}